// Round 1
// baseline (3497.495 us; speedup 1.0000x reference)
//
#include <hip/hip_runtime.h>
#include <math.h>

// Problem constants
#define BB   64
#define LL   256
#define EE   512
#define DD   512
#define BL   (BB * LL)      // 16384
#define MAX_DIST 11

// GEMM tiling
#define BM 64
#define BN 64
#define BK 16
#define LDP 68   // padded LDS row (float4-aligned: 68*4=272B, 272%16==0)

// ---------------------------------------------------------------------------
// Generic tiled fp32 GEMM:  C[b] = act( [A0|A1][b] * B[b] + bias )
//   A is row-major [M, K0+K1] given as two pointers (concat along K; A1 may
//   be null when K0==K).  NT=false: B row-major [K,N].  NT=true: B row-major
//   [N,K] (C = A * B^T).  M,N multiples of 64; K,K0 multiples of 16.
// ---------------------------------------------------------------------------
template <bool NT>
__global__ __launch_bounds__(256) void gemm_kernel(
    const float* __restrict__ A0, int K0, int lda0, long long bsA0,
    const float* __restrict__ A1, int lda1, long long bsA1,
    const float* __restrict__ B, int ldb, long long bsB,
    const float* __restrict__ bias,
    float* __restrict__ C, int ldc, long long bsC,
    int K, int relu)
{
    __shared__ float As[BK][LDP];
    __shared__ float Bs[BK][LDP];

    const int tid  = threadIdx.x;
    const int tx   = tid & 15;        // N micro-tile
    const int ty   = tid >> 4;        // M micro-tile
    const int row0 = blockIdx.y * BM;
    const int col0 = blockIdx.x * BN;
    const int b    = blockIdx.z;

    const float* A0b = A0 + (long long)b * bsA0;
    const float* A1b = A1 ? (A1 + (long long)b * bsA1) : nullptr;
    const float* Bb  = B + (long long)b * bsB;
    float*       Cb  = C + (long long)b * bsC;

    const int ar = tid >> 2;          // 0..63 tile row
    const int ak = (tid & 3) << 2;    // 0,4,8,12 k-vec
    const int br = tid >> 4;          // 0..15 (NN: k row)
    const int bc = (tid & 15) << 2;   // 0..60 (NN: n col)

    float acc[4][4] = {};

    for (int kk = 0; kk < K; kk += BK) {
        const float* Ap; int lda, kloc;
        if (kk < K0) { Ap = A0b; lda = lda0; kloc = kk; }
        else         { Ap = A1b; lda = lda1; kloc = kk - K0; }
        float4 av = *reinterpret_cast<const float4*>(
            Ap + (long long)(row0 + ar) * lda + kloc + ak);
        As[ak + 0][ar] = av.x;
        As[ak + 1][ar] = av.y;
        As[ak + 2][ar] = av.z;
        As[ak + 3][ar] = av.w;
        if (NT) {
            float4 bv = *reinterpret_cast<const float4*>(
                Bb + (long long)(col0 + ar) * ldb + kk + ak);
            Bs[ak + 0][ar] = bv.x;
            Bs[ak + 1][ar] = bv.y;
            Bs[ak + 2][ar] = bv.z;
            Bs[ak + 3][ar] = bv.w;
        } else {
            float4 bv = *reinterpret_cast<const float4*>(
                Bb + (long long)(kk + br) * ldb + col0 + bc);
            *reinterpret_cast<float4*>(&Bs[br][bc]) = bv;
        }
        __syncthreads();
#pragma unroll
        for (int k = 0; k < BK; ++k) {
            float4 a  = *reinterpret_cast<const float4*>(&As[k][ty << 2]);
            float4 bq = *reinterpret_cast<const float4*>(&Bs[k][tx << 2]);
            float am[4] = {a.x, a.y, a.z, a.w};
            float bm[4] = {bq.x, bq.y, bq.z, bq.w};
#pragma unroll
            for (int i = 0; i < 4; ++i)
#pragma unroll
                for (int j = 0; j < 4; ++j)
                    acc[i][j] = fmaf(am[i], bm[j], acc[i][j]);
        }
        __syncthreads();
    }

#pragma unroll
    for (int i = 0; i < 4; ++i) {
        float4 v;
        float* vv = reinterpret_cast<float*>(&v);
#pragma unroll
        for (int j = 0; j < 4; ++j) {
            float x = acc[i][j];
            if (bias) x += bias[col0 + (tx << 2) + j];
            if (relu) x = fmaxf(x, 0.0f);
            vv[j] = x;
        }
        *reinterpret_cast<float4*>(
            Cb + (long long)(row0 + (ty << 2) + i) * ldc + col0 + (tx << 2)) = v;
    }
}

// ---------------------------------------------------------------------------
// Embedding gather + mask.  grid = BL blocks, 128 threads; out row stride 1024
// (x goes into cols [0,512) of the concat buffer).
// ---------------------------------------------------------------------------
__global__ void embed_kernel(const int* __restrict__ tokens,
                             const float* __restrict__ W,
                             float* __restrict__ cat,
                             float* __restrict__ mask)
{
    const int row = blockIdx.x;
    const int t   = threadIdx.x;   // 0..127, one float4 each (512 floats)
    const int tok = tokens[row];
    if (t == 0) mask[row] = (tok != 0) ? 1.0f : 0.0f;
    const float4* src = reinterpret_cast<const float4*>(W + (long long)tok * EE);
    float4* dst = reinterpret_cast<float4*>(cat + (long long)row * (2 * EE));
    dst[t] = src[t];
}

// ---------------------------------------------------------------------------
// Block reduction helpers (256 threads)
// ---------------------------------------------------------------------------
__device__ __forceinline__ float block_max(float v, float* red, int tid)
{
    red[tid] = v; __syncthreads();
    for (int st = 128; st > 0; st >>= 1) {
        if (tid < st) red[tid] = fmaxf(red[tid], red[tid + st]);
        __syncthreads();
    }
    float r = red[0]; __syncthreads();
    return r;
}
__device__ __forceinline__ float block_sum(float v, float* red, int tid)
{
    red[tid] = v; __syncthreads();
    for (int st = 128; st > 0; st >>= 1) {
        if (tid < st) red[tid] += red[tid + st];
        __syncthreads();
    }
    float r = red[0]; __syncthreads();
    return r;
}

// ---------------------------------------------------------------------------
// Self-attention softmax (in place on S[b,q,:]):
//   s += dist_W[clip(j-q)] ; diag -> -inf ; masked key -> -1e9 ; softmax.
// grid = (L, B), block = 256
// ---------------------------------------------------------------------------
__global__ void self_softmax_kernel(float* __restrict__ S,
                                    const float* __restrict__ mask,
                                    const float* __restrict__ distW)
{
    __shared__ float red[256];
    const int q = blockIdx.x, b = blockIdx.y, j = threadIdx.x;
    float* row = S + ((long long)b * LL + q) * LL;
    int d = j - q;
    d = d > MAX_DIST ? MAX_DIST : (d < -MAX_DIST ? -MAX_DIST : d);
    float s = row[j] + distW[d + MAX_DIST];
    if (j == q) s = -INFINITY;
    if (mask[b * LL + j] == 0.0f) s = -1e9f;
    float mx = block_max(s, red, j);
    float e  = expf(s - mx);
    float sm = block_sum(e, red, j);
    row[j] = e / sm;
}

// Row softmax of z over keys (last dim) with key mask -> S2[b,p,:]
__global__ void row_softmax_kernel(const float* __restrict__ Z,
                                   float* __restrict__ S2,
                                   const float* __restrict__ maskK)
{
    __shared__ float red[256];
    const int p = blockIdx.x, b = blockIdx.y, j = threadIdx.x;
    const float* row = Z + ((long long)b * LL + p) * LL;
    float s = (maskK[b * LL + j] == 0.0f) ? -1e9f : row[j];
    float mx = block_max(s, red, j);
    float e  = expf(s - mx);
    float sm = block_sum(e, red, j);
    S2[((long long)b * LL + p) * LL + j] = e / sm;
}

// Column softmax of z over dim1 (p) with prem mask, written transposed:
//   S2[b,h,p] = softmax_p( z[b,p,h] masked )
__global__ void col_softmax_kernel(const float* __restrict__ Z,
                                   float* __restrict__ S2,
                                   const float* __restrict__ maskQ)
{
    __shared__ float red[256];
    const int h = blockIdx.x, b = blockIdx.y, p = threadIdx.x;
    float s = Z[((long long)b * LL + p) * LL + h];
    if (maskQ[b * LL + p] == 0.0f) s = -1e9f;
    float mx = block_max(s, red, p);
    float e  = expf(s - mx);
    float sm = block_sum(e, red, p);
    S2[((long long)b * LL + h) * LL + p] = e / sm;
}

// Masked sum over positions: R[b, colOff + c] = sum_r X[b,r,c]*mask[b,r]
// grid = (D/256, B), block = 256
__global__ void masked_reduce_kernel(const float* __restrict__ X,
                                     const float* __restrict__ mask,
                                     float* __restrict__ R, int colOff)
{
    const int b = blockIdx.y;
    const int c = blockIdx.x * 256 + threadIdx.x;
    float acc = 0.0f;
    for (int r = 0; r < LL; ++r)
        acc = fmaf(X[((long long)b * LL + r) * DD + c], mask[b * LL + r], acc);
    R[b * (2 * DD) + colOff + c] = acc;
}

// Final output: out[b,o] = sum_d G[b,d] * Wo[d,o].  1 block, 256 threads.
__global__ void out_kernel(const float* __restrict__ G,
                           const float* __restrict__ Wo,
                           float* __restrict__ out)
{
    const int t = threadIdx.x;
    if (t < BB * 3) {
        const int b = t / 3, o = t % 3;
        float acc = 0.0f;
        for (int d = 0; d < DD; ++d)
            acc = fmaf(G[b * DD + d], Wo[d * 3 + o], acc);
        out[t] = acc;
    }
}

// ---------------------------------------------------------------------------
// Host-side launcher
// ---------------------------------------------------------------------------
static inline void gemm(hipStream_t stream, bool nt,
                        const float* A0, int K0, int lda0, long long bsA0,
                        const float* A1, int lda1, long long bsA1,
                        const float* B, int ldb, long long bsB,
                        const float* bias,
                        float* C, int ldc, long long bsC,
                        int M, int N, int K, bool relu, int batch)
{
    dim3 grid(N / BN, M / BM, batch);
    dim3 block(256);
    if (nt)
        gemm_kernel<true><<<grid, block, 0, stream>>>(A0, K0, lda0, bsA0, A1, lda1, bsA1,
                                                      B, ldb, bsB, bias, C, ldc, bsC, K, relu ? 1 : 0);
    else
        gemm_kernel<false><<<grid, block, 0, stream>>>(A0, K0, lda0, bsA0, A1, lda1, bsA1,
                                                       B, ldb, bsB, bias, C, ldc, bsC, K, relu ? 1 : 0);
}

extern "C" void kernel_launch(void* const* d_in, const int* in_sizes, int n_in,
                              void* d_out, int out_size, void* d_ws, size_t ws_size,
                              hipStream_t stream)
{
    (void)in_sizes; (void)n_in; (void)out_size; (void)ws_size;

    const int*   prem_tok = (const int*)d_in[0];
    const int*   hypo_tok = (const int*)d_in[1];
    const float* embW = (const float*)d_in[2];
    const float* dW   = (const float*)d_in[3];
    const float* Ws1  = (const float*)d_in[4];
    const float* bs1  = (const float*)d_in[5];
    const float* Ws2  = (const float*)d_in[6];
    const float* bs2  = (const float*)d_in[7];
    const float* Wa1  = (const float*)d_in[8];
    const float* ba1  = (const float*)d_in[9];
    const float* Wa2  = (const float*)d_in[10];
    const float* ba2  = (const float*)d_in[11];
    const float* Wc1  = (const float*)d_in[12];
    const float* bc1  = (const float*)d_in[13];
    const float* Wc2  = (const float*)d_in[14];
    const float* bc2  = (const float*)d_in[15];
    const float* Wg1  = (const float*)d_in[16];
    const float* bg1  = (const float*)d_in[17];
    const float* Wg2  = (const float*)d_in[18];
    const float* bg2  = (const float*)d_in[19];
    const float* Wo   = (const float*)d_in[20];
    float* out = (float*)d_out;

    // Workspace carve-up (floats).  Total ~336 MB.
    float* ws = (float*)d_ws;
    size_t off = 0;
    auto alloc = [&](size_t n) { float* p = ws + off; off += (n + 3) & ~(size_t)3; return p; };
    float* P_CAT = alloc((size_t)BL * 2 * EE);  // [BL,1024]  x | ctx
    float* H_CAT = alloc((size_t)BL * 2 * EE);
    float* Hb    = alloc((size_t)BL * DD);      // MLP hidden
    float* Q1    = alloc((size_t)BL * DD);      // q / pq / prem_cmp
    float* Q2    = alloc((size_t)BL * DD);      // hk / hypo_cmp
    float* S     = alloc((size_t)BB * LL * LL); // scores / z
    float* S2    = alloc((size_t)BB * LL * LL); // softmaxed
    float* ATT   = alloc((size_t)BL * 2 * EE);  // attended (shared AH/AP)
    float* maskP = alloc(BL);
    float* maskH = alloc(BL);
    float* R     = alloc((size_t)BB * 2 * DD);  // reduced compare (concat)

    const long long bsQ = (long long)LL * DD;      // 131072
    const long long bsS = (long long)LL * LL;      // 65536
    const long long bsC = (long long)LL * 2 * EE;  // 262144

    // 1. embeddings + masks
    embed_kernel<<<dim3(BL), dim3(128), 0, stream>>>(prem_tok, embW, P_CAT, maskP);
    embed_kernel<<<dim3(BL), dim3(128), 0, stream>>>(hypo_tok, embW, H_CAT, maskH);

    // 2. self branch (prem then hypo)
    for (int s = 0; s < 2; ++s) {
        float* CAT = s == 0 ? P_CAT : H_CAT;
        float* MSK = s == 0 ? maskP : maskH;
        gemm(stream, false, CAT, EE, 2 * EE, 0, nullptr, 0, 0,
             Ws1, DD, 0, bs1, Hb, DD, 0, BL, DD, EE, true, 1);
        gemm(stream, false, Hb, DD, DD, 0, nullptr, 0, 0,
             Ws2, DD, 0, bs2, Q1, DD, 0, BL, DD, DD, true, 1);
        gemm(stream, true, Q1, DD, DD, bsQ, nullptr, 0, 0,
             Q1, DD, bsQ, nullptr, S, LL, bsS, LL, LL, DD, false, BB);
        self_softmax_kernel<<<dim3(LL, BB), dim3(256), 0, stream>>>(S, MSK, dW);
        gemm(stream, false, S, LL, LL, bsS, nullptr, 0, 0,
             CAT, 2 * EE, bsC, nullptr, CAT + EE, 2 * EE, bsC, LL, EE, LL, false, BB);
    }

    // 3. inter-attention projections
    gemm(stream, false, P_CAT, 2 * EE, 2 * EE, 0, nullptr, 0, 0,
         Wa1, DD, 0, ba1, Hb, DD, 0, BL, DD, 2 * EE, true, 1);
    gemm(stream, false, Hb, DD, DD, 0, nullptr, 0, 0,
         Wa2, DD, 0, ba2, Q1, DD, 0, BL, DD, DD, true, 1);
    gemm(stream, false, H_CAT, 2 * EE, 2 * EE, 0, nullptr, 0, 0,
         Wa1, DD, 0, ba1, Hb, DD, 0, BL, DD, 2 * EE, true, 1);
    gemm(stream, false, Hb, DD, DD, 0, nullptr, 0, 0,
         Wa2, DD, 0, ba2, Q2, DD, 0, BL, DD, DD, true, 1);
    // z = pq @ hk^T
    gemm(stream, true, Q1, DD, DD, bsQ, nullptr, 0, 0,
         Q2, DD, bsQ, nullptr, S, LL, bsS, LL, LL, DD, false, BB);

    // 4. prem side: softmax over hypo keys, attend, compare MLP
    row_softmax_kernel<<<dim3(LL, BB), dim3(256), 0, stream>>>(S, S2, maskH);
    gemm(stream, false, S2, LL, LL, bsS, nullptr, 0, 0,
         H_CAT, 2 * EE, bsC, nullptr, ATT, 2 * EE, bsC, LL, 2 * EE, LL, false, BB);
    gemm(stream, false, P_CAT, 2 * EE, 2 * EE, 0, ATT, 2 * EE, 0,
         Wc1, DD, 0, bc1, Hb, DD, 0, BL, DD, 4 * EE, true, 1);
    gemm(stream, false, Hb, DD, DD, 0, nullptr, 0, 0,
         Wc2, DD, 0, bc2, Q1, DD, 0, BL, DD, DD, true, 1);

    // 5. hypo side: softmax over prem keys (transposed), attend, compare MLP
    col_softmax_kernel<<<dim3(LL, BB), dim3(256), 0, stream>>>(S, S2, maskP);
    gemm(stream, false, S2, LL, LL, bsS, nullptr, 0, 0,
         P_CAT, 2 * EE, bsC, nullptr, ATT, 2 * EE, bsC, LL, 2 * EE, LL, false, BB);
    gemm(stream, false, H_CAT, 2 * EE, 2 * EE, 0, ATT, 2 * EE, 0,
         Wc1, DD, 0, bc1, Hb, DD, 0, BL, DD, 4 * EE, true, 1);
    gemm(stream, false, Hb, DD, DD, 0, nullptr, 0, 0,
         Wc2, DD, 0, bc2, Q2, DD, 0, BL, DD, DD, true, 1);

    // 6. masked position-sum -> R = [prem_cmp_sum | hypo_cmp_sum]  [64,1024]
    masked_reduce_kernel<<<dim3(DD / 256, BB), dim3(256), 0, stream>>>(Q1, maskP, R, 0);
    masked_reduce_kernel<<<dim3(DD / 256, BB), dim3(256), 0, stream>>>(Q2, maskH, R, DD);

    // 7. aggregate MLP + output
    gemm(stream, false, R, 2 * DD, 2 * DD, 0, nullptr, 0, 0,
         Wg1, DD, 0, bg1, Hb, DD, 0, BB, DD, 2 * DD, true, 1);
    gemm(stream, false, Hb, DD, DD, 0, nullptr, 0, 0,
         Wg2, DD, 0, bg2, Q1, DD, 0, BB, DD, DD, true, 1);
    out_kernel<<<dim3(1), dim3(256), 0, stream>>>(Q1, Wo, out);
}

// Round 2
// 1455.640 us; speedup vs baseline: 2.4027x; 2.4027x over previous
//
#include <hip/hip_runtime.h>
#include <math.h>

#define BB   64
#define LL   256
#define EE   512
#define DD   512
#define BL   (BB * LL)      // 16384
#define MAX_DIST 11

typedef __attribute__((ext_vector_type(8))) short bf16x8;
typedef __attribute__((ext_vector_type(4))) float f32x4;

__device__ __forceinline__ float bf2f(unsigned short u) {
    union { unsigned int u; float f; } v; v.u = ((unsigned int)u) << 16; return v.f;
}
__device__ __forceinline__ unsigned short f2bf(float f) {
    union { float f; unsigned int u; } v; v.f = f;
    unsigned int r = v.u + 0x7FFF + ((v.u >> 16) & 1);   // RNE
    return (unsigned short)(r >> 16);
}

#define GLOAD16(g, l)                                                          \
    __builtin_amdgcn_global_load_lds(                                          \
        (const __attribute__((address_space(1))) void*)(g),                    \
        (__attribute__((address_space(3))) void*)(l), 16, 0, 0)

// ---------------------------------------------------------------------------
// bf16 MFMA GEMM (m97 structure):  C = act( [A0|A1] * B^T + bias )
//   A row-major [M, K0+K1] bf16 (two-pointer concat along K; A1 null if K0==K)
//   B row-major [N, K] bf16  (i.e. already transposed)
//   C [M, N]: bf16 if OBF16 else fp32, fp32 accumulate.
//   M, N multiples of 128; K, K0 multiples of 32.
//   Block 256 thr = 4 waves, tile 128x128, BK=32, 16x16x32 MFMA, 4x4/wave.
// ---------------------------------------------------------------------------
template <bool OBF16>
__global__ __launch_bounds__(256) void bgemm_kernel(
    const unsigned short* __restrict__ A0, int K0, int lda0, long long bsA0,
    const unsigned short* __restrict__ A1, int lda1, long long bsA1,
    const unsigned short* __restrict__ B, int ldb, long long bsB,
    const float* __restrict__ bias,
    void* __restrict__ Cv, int ldc, long long bsC,
    int K, int relu)
{
    __shared__ unsigned short As[128 * 32];   // [row][k] rows of 32 bf16 = 64B
    __shared__ unsigned short Bs[128 * 32];   // [col][k]

    const int tid  = threadIdx.x;
    const int wave = tid >> 6;
    const int lane = tid & 63;
    const int quad = lane >> 4;
    const int l15  = lane & 15;
    const int wm   = (wave >> 1) * 64;        // wave's row offset in tile
    const int wn   = (wave & 1) * 64;         // wave's col offset in tile
    const int row0 = blockIdx.y * 128;
    const int col0 = blockIdx.x * 128;
    const int b    = blockIdx.z;

    const unsigned short* A0b = A0 + (long long)b * bsA0;
    const unsigned short* A1b = A1 ? (A1 + (long long)b * bsA1) : nullptr;
    const unsigned short* Bb  = B + (long long)b * bsB;

    // staging: chunk = it*256 + tid; r = chunk>>2 (tile row), cs = chunk&3 (k/8)
    const int r_st  = tid >> 2;
    const int cs_st = (tid & 3) * 8;

    f32x4 acc[4][4];
#pragma unroll
    for (int i = 0; i < 4; ++i)
#pragma unroll
        for (int j = 0; j < 4; ++j)
            acc[i][j] = (f32x4){0.f, 0.f, 0.f, 0.f};

    for (int kk = 0; kk < K; kk += 32) {
        const unsigned short* Ap; int lda, kloc;
        if (kk < K0) { Ap = A0b; lda = lda0; kloc = kk; }
        else         { Ap = A1b; lda = lda1; kloc = kk - K0; }
#pragma unroll
        for (int it = 0; it < 2; ++it) {
            const unsigned short* g =
                Ap + (long long)(row0 + it * 64 + r_st) * lda + kloc + cs_st;
            char* l = (char*)As + (it * 256 + wave * 64) * 16;
            GLOAD16(g, l);
        }
#pragma unroll
        for (int it = 0; it < 2; ++it) {
            const unsigned short* g =
                Bb + (long long)(col0 + it * 64 + r_st) * ldb + kk + cs_st;
            char* l = (char*)Bs + (it * 256 + wave * 64) * 16;
            GLOAD16(g, l);
        }
        __syncthreads();

        bf16x8 fa[4], fb[4];
#pragma unroll
        for (int mi = 0; mi < 4; ++mi)
            fa[mi] = *(const bf16x8*)&As[(wm + mi * 16 + l15) * 32 + quad * 8];
#pragma unroll
        for (int ni = 0; ni < 4; ++ni)
            fb[ni] = *(const bf16x8*)&Bs[(wn + ni * 16 + l15) * 32 + quad * 8];
#pragma unroll
        for (int mi = 0; mi < 4; ++mi)
#pragma unroll
            for (int ni = 0; ni < 4; ++ni)
                acc[mi][ni] = __builtin_amdgcn_mfma_f32_16x16x32_bf16(
                    fa[mi], fb[ni], acc[mi][ni], 0, 0, 0);
        __syncthreads();
    }

    // epilogue: C/D layout col=lane&15, row=quad*4+reg
#pragma unroll
    for (int mi = 0; mi < 4; ++mi)
#pragma unroll
        for (int ni = 0; ni < 4; ++ni) {
            const int colb = col0 + wn + ni * 16 + l15;
            float bv = bias ? bias[colb] : 0.f;
#pragma unroll
            for (int r = 0; r < 4; ++r) {
                const int row = row0 + wm + mi * 16 + quad * 4 + r;
                float x = acc[mi][ni][r] + bv;
                if (relu) x = fmaxf(x, 0.f);
                long long off = (long long)b * bsC + (long long)row * ldc + colb;
                if (OBF16) ((unsigned short*)Cv)[off] = f2bf(x);
                else       ((float*)Cv)[off] = x;
            }
        }
}

// ---------------------------------------------------------------------------
// Weight convert+transpose: W fp32 [K,N] -> WT bf16 [N,K]
// block (32,8), grid (N/32, K/32)
// ---------------------------------------------------------------------------
__global__ void wconv_kernel(const float* __restrict__ src,
                             unsigned short* __restrict__ dst, int K, int N)
{
    __shared__ float tile[32][33];
    const int n0 = blockIdx.x * 32, k0 = blockIdx.y * 32;
#pragma unroll
    for (int i = 0; i < 4; ++i)
        tile[threadIdx.y + i * 8][threadIdx.x] =
            src[(long long)(k0 + threadIdx.y + i * 8) * N + n0 + threadIdx.x];
    __syncthreads();
#pragma unroll
    for (int i = 0; i < 4; ++i)
        dst[(long long)(n0 + threadIdx.y + i * 8) * K + k0 + threadIdx.x] =
            f2bf(tile[threadIdx.x][threadIdx.y + i * 8]);
}

// Per-batch bf16 transpose: src [b*256+l][c] (stride lds_) -> dst[b][c][l]
// block (32,8), grid (C/32, 8, B)
__global__ void btrans_kernel(const unsigned short* __restrict__ src, int lds_,
                              unsigned short* __restrict__ dst, int C)
{
    __shared__ unsigned short tile[32][33];
    const int b = blockIdx.z;
    const int c0 = blockIdx.x * 32, l0 = blockIdx.y * 32;
    const unsigned short* s = src + (long long)b * 256 * lds_;
    unsigned short* d = dst + (long long)b * C * 256;
#pragma unroll
    for (int i = 0; i < 4; ++i)
        tile[threadIdx.y + i * 8][threadIdx.x] =
            s[(long long)(l0 + threadIdx.y + i * 8) * lds_ + c0 + threadIdx.x];
    __syncthreads();
#pragma unroll
    for (int i = 0; i < 4; ++i)
        d[(long long)(c0 + threadIdx.y + i * 8) * 256 + l0 + threadIdx.x] =
            tile[threadIdx.x][threadIdx.y + i * 8];
}

// ---------------------------------------------------------------------------
// Embedding gather + mask -> bf16 into cols [0,512) of CAT [BL,1024]
// ---------------------------------------------------------------------------
__global__ void embed_kernel(const int* __restrict__ tokens,
                             const float* __restrict__ W,
                             unsigned short* __restrict__ cat,
                             float* __restrict__ mask)
{
    const int row = blockIdx.x;
    const int t   = threadIdx.x;   // 0..127
    const int tok = tokens[row];
    if (t == 0) mask[row] = (tok != 0) ? 1.0f : 0.0f;
    float4 v = ((const float4*)(W + (long long)tok * EE))[t];
    ushort4 o;
    o.x = f2bf(v.x); o.y = f2bf(v.y); o.z = f2bf(v.z); o.w = f2bf(v.w);
    ((ushort4*)(cat + (long long)row * (2 * EE)))[t] = o;
}

// ---------------------------------------------------------------------------
// Softmax kernels (fp32 scores in, bf16 probs out), block 256
// ---------------------------------------------------------------------------
__device__ __forceinline__ float block_max(float v, float* red, int tid)
{
    red[tid] = v; __syncthreads();
    for (int st = 128; st > 0; st >>= 1) {
        if (tid < st) red[tid] = fmaxf(red[tid], red[tid + st]);
        __syncthreads();
    }
    float r = red[0]; __syncthreads();
    return r;
}
__device__ __forceinline__ float block_sum(float v, float* red, int tid)
{
    red[tid] = v; __syncthreads();
    for (int st = 128; st > 0; st >>= 1) {
        if (tid < st) red[tid] += red[tid + st];
        __syncthreads();
    }
    float r = red[0]; __syncthreads();
    return r;
}

__global__ void self_softmax_kernel(const float* __restrict__ S,
                                    unsigned short* __restrict__ SP,
                                    const float* __restrict__ mask,
                                    const float* __restrict__ distW)
{
    __shared__ float red[256];
    const int q = blockIdx.x, b = blockIdx.y, j = threadIdx.x;
    float s = S[((long long)b * LL + q) * LL + j];
    int d = j - q;
    d = d > MAX_DIST ? MAX_DIST : (d < -MAX_DIST ? -MAX_DIST : d);
    s += distW[d + MAX_DIST];
    if (j == q) s = -INFINITY;
    if (mask[b * LL + j] == 0.0f) s = -1e9f;
    float mx = block_max(s, red, j);
    float e  = expf(s - mx);
    float sm = block_sum(e, red, j);
    SP[((long long)b * LL + q) * LL + j] = f2bf(e / sm);
}

__global__ void row_softmax_kernel(const float* __restrict__ Z,
                                   unsigned short* __restrict__ SP,
                                   const float* __restrict__ maskK)
{
    __shared__ float red[256];
    const int p = blockIdx.x, b = blockIdx.y, j = threadIdx.x;
    float s = Z[((long long)b * LL + p) * LL + j];
    if (maskK[b * LL + j] == 0.0f) s = -1e9f;
    float mx = block_max(s, red, j);
    float e  = expf(s - mx);
    float sm = block_sum(e, red, j);
    SP[((long long)b * LL + p) * LL + j] = f2bf(e / sm);
}

// col softmax over p, output transposed: SP[b][h][p]
__global__ void col_softmax_kernel(const float* __restrict__ Z,
                                   unsigned short* __restrict__ SP,
                                   const float* __restrict__ maskQ)
{
    __shared__ float red[256];
    const int h = blockIdx.x, b = blockIdx.y, p = threadIdx.x;
    float s = Z[((long long)b * LL + p) * LL + h];
    if (maskQ[b * LL + p] == 0.0f) s = -1e9f;
    float mx = block_max(s, red, p);
    float e  = expf(s - mx);
    float sm = block_sum(e, red, p);
    SP[((long long)b * LL + h) * LL + p] = f2bf(e / sm);
}

// Masked position-sum (bf16 in, fp32 out): R32[b, colOff+c] = sum_r X[b,r,c]*m
__global__ void masked_reduce_kernel(const unsigned short* __restrict__ X,
                                     const float* __restrict__ mask,
                                     float* __restrict__ R32, int colOff)
{
    const int b = blockIdx.y;
    const int c = blockIdx.x * 256 + threadIdx.x;
    float acc = 0.0f;
    for (int r = 0; r < LL; ++r)
        acc = fmaf(bf2f(X[((long long)(b * LL + r)) * DD + c]),
                   mask[b * LL + r], acc);
    R32[b * (2 * DD) + colOff + c] = acc;
}

// Small fp32 MLP layer: Y[b,n] = relu(sum_k X[b,k]*W[k,n] + bias[n])
// grid 64 blocks, 512 threads
__global__ void mlp_small_kernel(const float* __restrict__ X,
                                 const float* __restrict__ W,
                                 const float* __restrict__ bias,
                                 float* __restrict__ Y, int Kin)
{
    const int b = blockIdx.x, n = threadIdx.x;
    float acc = bias[n];
    const float* x = X + (long long)b * Kin;
    for (int k = 0; k < Kin; ++k)
        acc = fmaf(x[k], W[(long long)k * 512 + n], acc);
    Y[b * 512 + n] = fmaxf(acc, 0.f);
}

// Final output: out[b,o] = sum_d G[b,d] * Wo[d,o]
__global__ void out_kernel(const float* __restrict__ G,
                           const float* __restrict__ Wo,
                           float* __restrict__ out)
{
    const int t = threadIdx.x;
    if (t < BB * 3) {
        const int b = t / 3, o = t % 3;
        float acc = 0.0f;
        for (int d = 0; d < DD; ++d)
            acc = fmaf(G[b * DD + d], Wo[d * 3 + o], acc);
        out[t] = acc;
    }
}

// ---------------------------------------------------------------------------
// Host-side launcher
// ---------------------------------------------------------------------------
static inline void bgemm(hipStream_t stream, bool obf16,
                         const unsigned short* A0, int K0, int lda0, long long bsA0,
                         const unsigned short* A1, int lda1, long long bsA1,
                         const unsigned short* B, int ldb, long long bsB,
                         const float* bias,
                         void* C, int ldc, long long bsC,
                         int M, int N, int K, bool relu, int batch)
{
    dim3 grid(N / 128, M / 128, batch);
    if (obf16)
        bgemm_kernel<true><<<grid, 256, 0, stream>>>(A0, K0, lda0, bsA0, A1, lda1, bsA1,
                                                     B, ldb, bsB, bias, C, ldc, bsC, K, relu);
    else
        bgemm_kernel<false><<<grid, 256, 0, stream>>>(A0, K0, lda0, bsA0, A1, lda1, bsA1,
                                                      B, ldb, bsB, bias, C, ldc, bsC, K, relu);
}

extern "C" void kernel_launch(void* const* d_in, const int* in_sizes, int n_in,
                              void* d_out, int out_size, void* d_ws, size_t ws_size,
                              hipStream_t stream)
{
    (void)in_sizes; (void)n_in; (void)out_size; (void)ws_size;

    const int*   prem_tok = (const int*)d_in[0];
    const int*   hypo_tok = (const int*)d_in[1];
    const float* embW = (const float*)d_in[2];
    const float* dW   = (const float*)d_in[3];
    const float* Ws1  = (const float*)d_in[4];
    const float* bs1  = (const float*)d_in[5];
    const float* Ws2  = (const float*)d_in[6];
    const float* bs2  = (const float*)d_in[7];
    const float* Wa1  = (const float*)d_in[8];
    const float* ba1  = (const float*)d_in[9];
    const float* Wa2  = (const float*)d_in[10];
    const float* ba2  = (const float*)d_in[11];
    const float* Wc1  = (const float*)d_in[12];
    const float* bc1  = (const float*)d_in[13];
    const float* Wc2  = (const float*)d_in[14];
    const float* bc2  = (const float*)d_in[15];
    const float* Wg1  = (const float*)d_in[16];
    const float* bg1  = (const float*)d_in[17];
    const float* Wg2  = (const float*)d_in[18];
    const float* bg2  = (const float*)d_in[19];
    const float* Wo   = (const float*)d_in[20];
    float* out = (float*)d_out;

    // ---- workspace carve-up (bytes) ----
    char* ws = (char*)d_ws;
    size_t off = 0;
    auto alloc = [&](size_t bytes) {
        char* p = ws + off; off += (bytes + 255) & ~(size_t)255; return p;
    };
    unsigned short* P_CAT = (unsigned short*)alloc((size_t)BL * 1024 * 2);
    unsigned short* H_CAT = (unsigned short*)alloc((size_t)BL * 1024 * 2);
    unsigned short* VT1   = (unsigned short*)alloc((size_t)BB * 1024 * 256 * 2);
    unsigned short* VT2   = (unsigned short*)alloc((size_t)BB * 1024 * 256 * 2);
    unsigned short* Hb    = (unsigned short*)alloc((size_t)BL * 512 * 2);
    unsigned short* Q1    = (unsigned short*)alloc((size_t)BL * 512 * 2);
    unsigned short* Q2    = (unsigned short*)alloc((size_t)BL * 512 * 2);
    unsigned short* ATT   = (unsigned short*)alloc((size_t)BL * 1024 * 2);
    float*          S     = (float*)alloc((size_t)BB * LL * LL * 4);
    unsigned short* SP    = (unsigned short*)alloc((size_t)BB * LL * LL * 2);
    float*          maskP = (float*)alloc(BL * 4);
    float*          maskH = (float*)alloc(BL * 4);
    float*          R32   = (float*)alloc((size_t)BB * 1024 * 4);
    float*          H64   = (float*)alloc((size_t)BB * 512 * 4);
    float*          G     = (float*)alloc((size_t)BB * 512 * 4);
    unsigned short* WTs1  = (unsigned short*)alloc((size_t)512 * 512 * 2);
    unsigned short* WTs2  = (unsigned short*)alloc((size_t)512 * 512 * 2);
    unsigned short* WTa1  = (unsigned short*)alloc((size_t)1024 * 512 * 2);
    unsigned short* WTa2  = (unsigned short*)alloc((size_t)512 * 512 * 2);
    unsigned short* WTc1  = (unsigned short*)alloc((size_t)2048 * 512 * 2);
    unsigned short* WTc2  = (unsigned short*)alloc((size_t)512 * 512 * 2);

    const long long bsQ = (long long)LL * DD;       // 131072
    const long long bsS = (long long)LL * LL;       // 65536
    const long long bsC = (long long)LL * 1024;     // 262144

    dim3 tb(32, 8);

    // 0. weight convert + transpose to [N][K] bf16
    wconv_kernel<<<dim3(16, 16), tb, 0, stream>>>(Ws1, WTs1, 512, 512);
    wconv_kernel<<<dim3(16, 16), tb, 0, stream>>>(Ws2, WTs2, 512, 512);
    wconv_kernel<<<dim3(16, 32), tb, 0, stream>>>(Wa1, WTa1, 1024, 512);
    wconv_kernel<<<dim3(16, 16), tb, 0, stream>>>(Wa2, WTa2, 512, 512);
    wconv_kernel<<<dim3(16, 64), tb, 0, stream>>>(Wc1, WTc1, 2048, 512);
    wconv_kernel<<<dim3(16, 16), tb, 0, stream>>>(Wc2, WTc2, 512, 512);

    // 1. embeddings + masks
    embed_kernel<<<BL, 128, 0, stream>>>(prem_tok, embW, P_CAT, maskP);
    embed_kernel<<<BL, 128, 0, stream>>>(hypo_tok, embW, H_CAT, maskH);

    // 2. self branch (prem, hypo)
    for (int s = 0; s < 2; ++s) {
        unsigned short* CAT = s == 0 ? P_CAT : H_CAT;
        float*          MSK = s == 0 ? maskP : maskH;
        bgemm(stream, true, CAT, 512, 1024, 0, nullptr, 0, 0,
              WTs1, 512, 0, bs1, Hb, 512, 0, BL, 512, 512, true, 1);
        bgemm(stream, true, Hb, 512, 512, 0, nullptr, 0, 0,
              WTs2, 512, 0, bs2, Q1, 512, 0, BL, 512, 512, true, 1);
        // x^T (cols 0..511) per batch -> VT1
        btrans_kernel<<<dim3(16, 8, BB), tb, 0, stream>>>(CAT, 1024, VT1, 512);
        // scores = q @ q^T  (fp32 out)
        bgemm(stream, false, Q1, 512, 512, bsQ, nullptr, 0, 0,
              Q1, 512, bsQ, nullptr, S, 256, bsS, 256, 256, 512, false, BB);
        self_softmax_kernel<<<dim3(LL, BB), 256, 0, stream>>>(S, SP, MSK, dW);
        // ctx = att @ x  -> CAT cols [512,1024)
        bgemm(stream, true, SP, 256, 256, bsS, nullptr, 0, 0,
              VT1, 256, (long long)512 * 256, nullptr,
              CAT + 512, 1024, bsC, 256, 512, 256, false, BB);
    }

    // 3. full V^T per batch (after self branches complete)
    btrans_kernel<<<dim3(32, 8, BB), tb, 0, stream>>>(P_CAT, 1024, VT1, 1024);
    btrans_kernel<<<dim3(32, 8, BB), tb, 0, stream>>>(H_CAT, 1024, VT2, 1024);

    // 4. inter-attention projections
    bgemm(stream, true, P_CAT, 1024, 1024, 0, nullptr, 0, 0,
          WTa1, 1024, 0, ba1, Hb, 512, 0, BL, 512, 1024, true, 1);
    bgemm(stream, true, Hb, 512, 512, 0, nullptr, 0, 0,
          WTa2, 512, 0, ba2, Q1, 512, 0, BL, 512, 512, true, 1);
    bgemm(stream, true, H_CAT, 1024, 1024, 0, nullptr, 0, 0,
          WTa1, 1024, 0, ba1, Hb, 512, 0, BL, 512, 1024, true, 1);
    bgemm(stream, true, Hb, 512, 512, 0, nullptr, 0, 0,
          WTa2, 512, 0, ba2, Q2, 512, 0, BL, 512, 512, true, 1);
    // z = pq @ hk^T (fp32)
    bgemm(stream, false, Q1, 512, 512, bsQ, nullptr, 0, 0,
          Q2, 512, bsQ, nullptr, S, 256, bsS, 256, 256, 512, false, BB);

    // 5. prem side
    row_softmax_kernel<<<dim3(LL, BB), 256, 0, stream>>>(S, SP, maskH);
    bgemm(stream, true, SP, 256, 256, bsS, nullptr, 0, 0,
          VT2, 256, (long long)1024 * 256, nullptr,
          ATT, 1024, bsC, 256, 1024, 256, false, BB);
    bgemm(stream, true, P_CAT, 1024, 1024, 0, ATT, 1024, 0,
          WTc1, 2048, 0, bc1, Hb, 512, 0, BL, 512, 2048, true, 1);
    bgemm(stream, true, Hb, 512, 512, 0, nullptr, 0, 0,
          WTc2, 512, 0, bc2, Q1, 512, 0, BL, 512, 512, true, 1);

    // 6. hypo side
    col_softmax_kernel<<<dim3(LL, BB), 256, 0, stream>>>(S, SP, maskP);
    bgemm(stream, true, SP, 256, 256, bsS, nullptr, 0, 0,
          VT1, 256, (long long)1024 * 256, nullptr,
          ATT, 1024, bsC, 256, 1024, 256, false, BB);
    bgemm(stream, true, H_CAT, 1024, 1024, 0, ATT, 1024, 0,
          WTc1, 2048, 0, bc1, Hb, 512, 0, BL, 512, 2048, true, 1);
    bgemm(stream, true, Hb, 512, 512, 0, nullptr, 0, 0,
          WTc2, 512, 0, bc2, Q2, 512, 0, BL, 512, 512, true, 1);

    // 7. masked position-sum (fp32) -> R32 [64,1024]
    masked_reduce_kernel<<<dim3(2, BB), 256, 0, stream>>>(Q1, maskP, R32, 0);
    masked_reduce_kernel<<<dim3(2, BB), 256, 0, stream>>>(Q2, maskH, R32, 512);

    // 8. aggregate MLP (fp32) + output
    mlp_small_kernel<<<BB, 512, 0, stream>>>(R32, Wg1, bg1, H64, 1024);
    mlp_small_kernel<<<BB, 512, 0, stream>>>(H64, Wg2, bg2, G, 512);
    out_kernel<<<1, 256, 0, stream>>>(G, Wo, out);
}

// Round 3
// 881.523 us; speedup vs baseline: 3.9676x; 1.6513x over previous
//
#include <hip/hip_runtime.h>
#include <math.h>

#define BB   64
#define LL   256
#define EE   512
#define DD   512
#define BL   (BB * LL)      // 16384
#define MAX_DIST 11

typedef __attribute__((ext_vector_type(8))) short bf16x8;
typedef __attribute__((ext_vector_type(4))) float f32x4;

__device__ __forceinline__ float bf2f(unsigned short u) {
    union { unsigned int u; float f; } v; v.u = ((unsigned int)u) << 16; return v.f;
}
__device__ __forceinline__ unsigned short f2bf(float f) {
    union { float f; unsigned int u; } v; v.f = f;
    unsigned int r = v.u + 0x7FFF + ((v.u >> 16) & 1);   // RNE
    return (unsigned short)(r >> 16);
}

#define GLOAD16(g, l)                                                          \
    __builtin_amdgcn_global_load_lds(                                          \
        (const __attribute__((address_space(1))) void*)(g),                    \
        (__attribute__((address_space(3))) void*)(l), 16, 0, 0)

// ---------------------------------------------------------------------------
// bf16 MFMA GEMM (m97 structure):  C = act( [A0|A1] * B^T + bias )
//   A row-major [M, K0+K1] bf16 (two-pointer concat along K; A1 null if K0==K)
//   B row-major [N, K] bf16  (i.e. already transposed)
//   C [M, N]: bf16 if OBF16 else fp32, fp32 accumulate.
//   M, N multiples of 128; K, K0 multiples of 32.
//   Block 256 thr = 4 waves, tile 128x128, BK=32, 16x16x32 MFMA, 4x4/wave.
// ---------------------------------------------------------------------------
template <bool OBF16>
__global__ __launch_bounds__(256) void bgemm_kernel(
    const unsigned short* __restrict__ A0, int K0, int lda0, long long bsA0,
    const unsigned short* __restrict__ A1, int lda1, long long bsA1,
    const unsigned short* __restrict__ B, int ldb, long long bsB,
    const float* __restrict__ bias,
    void* __restrict__ Cv, int ldc, long long bsC,
    int K, int relu)
{
    __shared__ unsigned short As[128 * 32];   // [row][k] rows of 32 bf16 = 64B
    __shared__ unsigned short Bs[128 * 32];   // [col][k]

    const int tid  = threadIdx.x;
    const int wave = tid >> 6;
    const int lane = tid & 63;
    const int quad = lane >> 4;
    const int l15  = lane & 15;
    const int wm   = (wave >> 1) * 64;        // wave's row offset in tile
    const int wn   = (wave & 1) * 64;         // wave's col offset in tile
    const int row0 = blockIdx.y * 128;
    const int col0 = blockIdx.x * 128;
    const int b    = blockIdx.z;

    const unsigned short* A0b = A0 + (long long)b * bsA0;
    const unsigned short* A1b = A1 ? (A1 + (long long)b * bsA1) : nullptr;
    const unsigned short* Bb  = B + (long long)b * bsB;

    const int r_st  = tid >> 2;
    const int cs_st = (tid & 3) * 8;

    f32x4 acc[4][4];
#pragma unroll
    for (int i = 0; i < 4; ++i)
#pragma unroll
        for (int j = 0; j < 4; ++j)
            acc[i][j] = (f32x4){0.f, 0.f, 0.f, 0.f};

    for (int kk = 0; kk < K; kk += 32) {
        const unsigned short* Ap; int lda, kloc;
        if (kk < K0) { Ap = A0b; lda = lda0; kloc = kk; }
        else         { Ap = A1b; lda = lda1; kloc = kk - K0; }
#pragma unroll
        for (int it = 0; it < 2; ++it) {
            const unsigned short* g =
                Ap + (long long)(row0 + it * 64 + r_st) * lda + kloc + cs_st;
            char* l = (char*)As + (it * 256 + wave * 64) * 16;
            GLOAD16(g, l);
        }
#pragma unroll
        for (int it = 0; it < 2; ++it) {
            const unsigned short* g =
                Bb + (long long)(col0 + it * 64 + r_st) * ldb + kk + cs_st;
            char* l = (char*)Bs + (it * 256 + wave * 64) * 16;
            GLOAD16(g, l);
        }
        __syncthreads();

        bf16x8 fa[4], fb[4];
#pragma unroll
        for (int mi = 0; mi < 4; ++mi)
            fa[mi] = *(const bf16x8*)&As[(wm + mi * 16 + l15) * 32 + quad * 8];
#pragma unroll
        for (int ni = 0; ni < 4; ++ni)
            fb[ni] = *(const bf16x8*)&Bs[(wn + ni * 16 + l15) * 32 + quad * 8];
#pragma unroll
        for (int mi = 0; mi < 4; ++mi)
#pragma unroll
            for (int ni = 0; ni < 4; ++ni)
                acc[mi][ni] = __builtin_amdgcn_mfma_f32_16x16x32_bf16(
                    fa[mi], fb[ni], acc[mi][ni], 0, 0, 0);
        __syncthreads();
    }

    // epilogue: C/D layout col=lane&15, row=quad*4+reg
#pragma unroll
    for (int mi = 0; mi < 4; ++mi)
#pragma unroll
        for (int ni = 0; ni < 4; ++ni) {
            const int colb = col0 + wn + ni * 16 + l15;
            float bv = bias ? bias[colb] : 0.f;
#pragma unroll
            for (int r = 0; r < 4; ++r) {
                const int row = row0 + wm + mi * 16 + quad * 4 + r;
                float x = acc[mi][ni][r] + bv;
                if (relu) x = fmaxf(x, 0.f);
                long long off = (long long)b * bsC + (long long)row * ldc + colb;
                if (OBF16) ((unsigned short*)Cv)[off] = f2bf(x);
                else       ((float*)Cv)[off] = x;
            }
        }
}

// ---------------------------------------------------------------------------
// Weight convert+transpose: W fp32 [K,N] -> WT bf16 [N,K]
// ---------------------------------------------------------------------------
__global__ void wconv_kernel(const float* __restrict__ src,
                             unsigned short* __restrict__ dst, int K, int N)
{
    __shared__ float tile[32][33];
    const int n0 = blockIdx.x * 32, k0 = blockIdx.y * 32;
#pragma unroll
    for (int i = 0; i < 4; ++i)
        tile[threadIdx.y + i * 8][threadIdx.x] =
            src[(long long)(k0 + threadIdx.y + i * 8) * N + n0 + threadIdx.x];
    __syncthreads();
#pragma unroll
    for (int i = 0; i < 4; ++i)
        dst[(long long)(n0 + threadIdx.y + i * 8) * K + k0 + threadIdx.x] =
            f2bf(tile[threadIdx.x][threadIdx.y + i * 8]);
}

// Per-batch bf16 transpose: src [b*256+l][c] (stride lds_) -> dst[b][c][l]
__global__ void btrans_kernel(const unsigned short* __restrict__ src, int lds_,
                              unsigned short* __restrict__ dst, int C)
{
    __shared__ unsigned short tile[32][33];
    const int b = blockIdx.z;
    const int c0 = blockIdx.x * 32, l0 = blockIdx.y * 32;
    const unsigned short* s = src + (long long)b * 256 * lds_;
    unsigned short* d = dst + (long long)b * C * 256;
#pragma unroll
    for (int i = 0; i < 4; ++i)
        tile[threadIdx.y + i * 8][threadIdx.x] =
            s[(long long)(l0 + threadIdx.y + i * 8) * lds_ + c0 + threadIdx.x];
    __syncthreads();
#pragma unroll
    for (int i = 0; i < 4; ++i)
        d[(long long)(c0 + threadIdx.y + i * 8) * 256 + l0 + threadIdx.x] =
            tile[threadIdx.x][threadIdx.y + i * 8];
}

// ---------------------------------------------------------------------------
// Embedding gather + mask -> bf16 into cols [0,512) of CAT [BL,1024]
// ---------------------------------------------------------------------------
__global__ void embed_kernel(const int* __restrict__ tokens,
                             const float* __restrict__ W,
                             unsigned short* __restrict__ cat,
                             float* __restrict__ mask)
{
    const int row = blockIdx.x;
    const int t   = threadIdx.x;   // 0..127
    const int tok = tokens[row];
    if (t == 0) mask[row] = (tok != 0) ? 1.0f : 0.0f;
    float4 v = ((const float4*)(W + (long long)tok * EE))[t];
    ushort4 o;
    o.x = f2bf(v.x); o.y = f2bf(v.y); o.z = f2bf(v.z); o.w = f2bf(v.w);
    ((ushort4*)(cat + (long long)row * (2 * EE)))[t] = o;
}

// ---------------------------------------------------------------------------
// Softmax kernels (fp32 scores in, bf16 probs out), block 256
// ---------------------------------------------------------------------------
__device__ __forceinline__ float block_max(float v, float* red, int tid)
{
    red[tid] = v; __syncthreads();
    for (int st = 128; st > 0; st >>= 1) {
        if (tid < st) red[tid] = fmaxf(red[tid], red[tid + st]);
        __syncthreads();
    }
    float r = red[0]; __syncthreads();
    return r;
}
__device__ __forceinline__ float block_sum(float v, float* red, int tid)
{
    red[tid] = v; __syncthreads();
    for (int st = 128; st > 0; st >>= 1) {
        if (tid < st) red[tid] += red[tid + st];
        __syncthreads();
    }
    float r = red[0]; __syncthreads();
    return r;
}

__global__ void self_softmax_kernel(const float* __restrict__ S,
                                    unsigned short* __restrict__ SP,
                                    const float* __restrict__ mask,
                                    const float* __restrict__ distW)
{
    __shared__ float red[256];
    const int q = blockIdx.x, b = blockIdx.y, j = threadIdx.x;
    float s = S[((long long)b * LL + q) * LL + j];
    int d = j - q;
    d = d > MAX_DIST ? MAX_DIST : (d < -MAX_DIST ? -MAX_DIST : d);
    s += distW[d + MAX_DIST];
    if (j == q) s = -INFINITY;
    if (mask[b * LL + j] == 0.0f) s = -1e9f;
    float mx = block_max(s, red, j);
    float e  = expf(s - mx);
    float sm = block_sum(e, red, j);
    SP[((long long)b * LL + q) * LL + j] = f2bf(e / sm);
}

__global__ void row_softmax_kernel(const float* __restrict__ Z,
                                   unsigned short* __restrict__ SP,
                                   const float* __restrict__ maskK)
{
    __shared__ float red[256];
    const int p = blockIdx.x, b = blockIdx.y, j = threadIdx.x;
    float s = Z[((long long)b * LL + p) * LL + j];
    if (maskK[b * LL + j] == 0.0f) s = -1e9f;
    float mx = block_max(s, red, j);
    float e  = expf(s - mx);
    float sm = block_sum(e, red, j);
    SP[((long long)b * LL + p) * LL + j] = f2bf(e / sm);
}

// col softmax over p, output transposed: SP[b][h][p]
__global__ void col_softmax_kernel(const float* __restrict__ Z,
                                   unsigned short* __restrict__ SP,
                                   const float* __restrict__ maskQ)
{
    __shared__ float red[256];
    const int h = blockIdx.x, b = blockIdx.y, p = threadIdx.x;
    float s = Z[((long long)b * LL + p) * LL + h];
    if (maskQ[b * LL + p] == 0.0f) s = -1e9f;
    float mx = block_max(s, red, p);
    float e  = expf(s - mx);
    float sm = block_sum(e, red, p);
    SP[((long long)b * LL + h) * LL + p] = f2bf(e / sm);
}

// Masked position-sum (bf16 in, fp32 out): R32[b, colOff+c] = sum_r X[b,r,c]*m
// 4 independent accumulator chains for MLP
__global__ void masked_reduce_kernel(const unsigned short* __restrict__ X,
                                     const float* __restrict__ mask,
                                     float* __restrict__ R32, int colOff)
{
    const int b = blockIdx.y;
    const int c = blockIdx.x * 256 + threadIdx.x;
    float a0 = 0.f, a1 = 0.f, a2 = 0.f, a3 = 0.f;
    const unsigned short* xb = X + ((long long)b * LL) * DD + c;
    const float* mb = mask + b * LL;
#pragma unroll 4
    for (int r = 0; r < 64; ++r) {
        a0 = fmaf(bf2f(xb[(r       ) * DD]), mb[r      ], a0);
        a1 = fmaf(bf2f(xb[(r +  64) * DD]), mb[r +  64], a1);
        a2 = fmaf(bf2f(xb[(r + 128) * DD]), mb[r + 128], a2);
        a3 = fmaf(bf2f(xb[(r + 192) * DD]), mb[r + 192], a3);
    }
    R32[b * (2 * DD) + colOff + c] = (a0 + a1) + (a2 + a3);
}

// Parallel small fp32 MLP layer: Y[b,n] = relu(sum_k X[b,k]*W[k,512+n]+bias)
// grid (512/64, BB), block 256 = 64 n x 4 k-slices
__global__ __launch_bounds__(256) void mlp_par_kernel(
    const float* __restrict__ X, const float* __restrict__ W,
    const float* __restrict__ bias, float* __restrict__ Y, int Kin)
{
    __shared__ float red[4][64];
    const int b  = blockIdx.y;
    const int n  = blockIdx.x * 64 + (threadIdx.x & 63);
    const int ts = threadIdx.x >> 6;       // 0..3
    const int kc = Kin >> 2;
    const float* x = X + (long long)b * Kin + ts * kc;
    const float* w = W + (long long)(ts * kc) * 512 + n;
    float a0 = 0.f, a1 = 0.f;
#pragma unroll 8
    for (int k = 0; k < kc; k += 2) {
        a0 = fmaf(x[k],     w[(long long)k * 512],        a0);
        a1 = fmaf(x[k + 1], w[(long long)(k + 1) * 512],  a1);
    }
    red[ts][threadIdx.x & 63] = a0 + a1;
    __syncthreads();
    if (ts == 0) {
        float v = red[0][threadIdx.x] + red[1][threadIdx.x] +
                  red[2][threadIdx.x] + red[3][threadIdx.x] + bias[n];
        Y[b * 512 + n] = fmaxf(v, 0.f);
    }
}

// Final output: one wave per (b,o).  grid 48 blocks x 256 thr = 192 waves.
__global__ void out_kernel(const float* __restrict__ G,
                           const float* __restrict__ Wo,
                           float* __restrict__ out)
{
    const int wid  = blockIdx.x * 4 + (threadIdx.x >> 6);   // 0..191
    const int lane = threadIdx.x & 63;
    const int b = wid / 3, o = wid % 3;
    float acc = 0.f;
#pragma unroll
    for (int j = 0; j < 8; ++j) {
        int d = lane + j * 64;
        acc = fmaf(G[b * DD + d], Wo[d * 3 + o], acc);
    }
#pragma unroll
    for (int st = 32; st > 0; st >>= 1)
        acc += __shfl_down(acc, st, 64);
    if (lane == 0) out[wid] = acc;
}

// ---------------------------------------------------------------------------
// Host-side launcher
// ---------------------------------------------------------------------------
static inline void bgemm(hipStream_t stream, bool obf16,
                         const unsigned short* A0, int K0, int lda0, long long bsA0,
                         const unsigned short* A1, int lda1, long long bsA1,
                         const unsigned short* B, int ldb, long long bsB,
                         const float* bias,
                         void* C, int ldc, long long bsC,
                         int M, int N, int K, bool relu, int batch)
{
    dim3 grid(N / 128, M / 128, batch);
    if (obf16)
        bgemm_kernel<true><<<grid, 256, 0, stream>>>(A0, K0, lda0, bsA0, A1, lda1, bsA1,
                                                     B, ldb, bsB, bias, C, ldc, bsC, K, relu);
    else
        bgemm_kernel<false><<<grid, 256, 0, stream>>>(A0, K0, lda0, bsA0, A1, lda1, bsA1,
                                                      B, ldb, bsB, bias, C, ldc, bsC, K, relu);
}

extern "C" void kernel_launch(void* const* d_in, const int* in_sizes, int n_in,
                              void* d_out, int out_size, void* d_ws, size_t ws_size,
                              hipStream_t stream)
{
    (void)in_sizes; (void)n_in; (void)out_size; (void)ws_size;

    const int*   prem_tok = (const int*)d_in[0];
    const int*   hypo_tok = (const int*)d_in[1];
    const float* embW = (const float*)d_in[2];
    const float* dW   = (const float*)d_in[3];
    const float* Ws1  = (const float*)d_in[4];
    const float* bs1  = (const float*)d_in[5];
    const float* Ws2  = (const float*)d_in[6];
    const float* bs2  = (const float*)d_in[7];
    const float* Wa1  = (const float*)d_in[8];
    const float* ba1  = (const float*)d_in[9];
    const float* Wa2  = (const float*)d_in[10];
    const float* ba2  = (const float*)d_in[11];
    const float* Wc1  = (const float*)d_in[12];
    const float* bc1  = (const float*)d_in[13];
    const float* Wc2  = (const float*)d_in[14];
    const float* bc2  = (const float*)d_in[15];
    const float* Wg1  = (const float*)d_in[16];
    const float* bg1  = (const float*)d_in[17];
    const float* Wg2  = (const float*)d_in[18];
    const float* bg2  = (const float*)d_in[19];
    const float* Wo   = (const float*)d_in[20];
    float* out = (float*)d_out;

    // ---- workspace carve-up (bytes) ----
    char* ws = (char*)d_ws;
    size_t off = 0;
    auto alloc = [&](size_t bytes) {
        char* p = ws + off; off += (bytes + 255) & ~(size_t)255; return p;
    };
    unsigned short* P_CAT = (unsigned short*)alloc((size_t)BL * 1024 * 2);
    unsigned short* H_CAT = (unsigned short*)alloc((size_t)BL * 1024 * 2);
    unsigned short* VT1   = (unsigned short*)alloc((size_t)BB * 1024 * 256 * 2);
    unsigned short* VT2   = (unsigned short*)alloc((size_t)BB * 1024 * 256 * 2);
    unsigned short* Hb    = (unsigned short*)alloc((size_t)BL * 512 * 2);
    unsigned short* Q1    = (unsigned short*)alloc((size_t)BL * 512 * 2);
    unsigned short* Q2    = (unsigned short*)alloc((size_t)BL * 512 * 2);
    unsigned short* ATT   = (unsigned short*)alloc((size_t)BL * 1024 * 2);
    float*          S     = (float*)alloc((size_t)BB * LL * LL * 4);
    unsigned short* SP    = (unsigned short*)alloc((size_t)BB * LL * LL * 2);
    float*          maskP = (float*)alloc(BL * 4);
    float*          maskH = (float*)alloc(BL * 4);
    float*          R32   = (float*)alloc((size_t)BB * 1024 * 4);
    float*          H64   = (float*)alloc((size_t)BB * 512 * 4);
    float*          G     = (float*)alloc((size_t)BB * 512 * 4);
    unsigned short* WTs1  = (unsigned short*)alloc((size_t)512 * 512 * 2);
    unsigned short* WTs2  = (unsigned short*)alloc((size_t)512 * 512 * 2);
    unsigned short* WTa1  = (unsigned short*)alloc((size_t)1024 * 512 * 2);
    unsigned short* WTa2  = (unsigned short*)alloc((size_t)512 * 512 * 2);
    unsigned short* WTc1  = (unsigned short*)alloc((size_t)2048 * 512 * 2);
    unsigned short* WTc2  = (unsigned short*)alloc((size_t)512 * 512 * 2);

    const long long bsQ = (long long)LL * DD;       // 131072
    const long long bsS = (long long)LL * LL;       // 65536
    const long long bsC = (long long)LL * 1024;     // 262144

    dim3 tb(32, 8);

    // 0. weight convert + transpose to [N][K] bf16
    wconv_kernel<<<dim3(16, 16), tb, 0, stream>>>(Ws1, WTs1, 512, 512);
    wconv_kernel<<<dim3(16, 16), tb, 0, stream>>>(Ws2, WTs2, 512, 512);
    wconv_kernel<<<dim3(16, 32), tb, 0, stream>>>(Wa1, WTa1, 1024, 512);
    wconv_kernel<<<dim3(16, 16), tb, 0, stream>>>(Wa2, WTa2, 512, 512);
    wconv_kernel<<<dim3(16, 64), tb, 0, stream>>>(Wc1, WTc1, 2048, 512);
    wconv_kernel<<<dim3(16, 16), tb, 0, stream>>>(Wc2, WTc2, 512, 512);

    // 1. embeddings + masks
    embed_kernel<<<BL, 128, 0, stream>>>(prem_tok, embW, P_CAT, maskP);
    embed_kernel<<<BL, 128, 0, stream>>>(hypo_tok, embW, H_CAT, maskH);

    // 2. self branch (prem, hypo)
    for (int s = 0; s < 2; ++s) {
        unsigned short* CAT = s == 0 ? P_CAT : H_CAT;
        float*          MSK = s == 0 ? maskP : maskH;
        bgemm(stream, true, CAT, 512, 1024, 0, nullptr, 0, 0,
              WTs1, 512, 0, bs1, Hb, 512, 0, BL, 512, 512, true, 1);
        bgemm(stream, true, Hb, 512, 512, 0, nullptr, 0, 0,
              WTs2, 512, 0, bs2, Q1, 512, 0, BL, 512, 512, true, 1);
        btrans_kernel<<<dim3(16, 8, BB), tb, 0, stream>>>(CAT, 1024, VT1, 512);
        bgemm(stream, false, Q1, 512, 512, bsQ, nullptr, 0, 0,
              Q1, 512, bsQ, nullptr, S, 256, bsS, 256, 256, 512, false, BB);
        self_softmax_kernel<<<dim3(LL, BB), 256, 0, stream>>>(S, SP, MSK, dW);
        bgemm(stream, true, SP, 256, 256, bsS, nullptr, 0, 0,
              VT1, 256, (long long)512 * 256, nullptr,
              CAT + 512, 1024, bsC, 256, 512, 256, false, BB);
    }

    // 3. full V^T per batch
    btrans_kernel<<<dim3(32, 8, BB), tb, 0, stream>>>(P_CAT, 1024, VT1, 1024);
    btrans_kernel<<<dim3(32, 8, BB), tb, 0, stream>>>(H_CAT, 1024, VT2, 1024);

    // 4. inter-attention projections
    bgemm(stream, true, P_CAT, 1024, 1024, 0, nullptr, 0, 0,
          WTa1, 1024, 0, ba1, Hb, 512, 0, BL, 512, 1024, true, 1);
    bgemm(stream, true, Hb, 512, 512, 0, nullptr, 0, 0,
          WTa2, 512, 0, ba2, Q1, 512, 0, BL, 512, 512, true, 1);
    bgemm(stream, true, H_CAT, 1024, 1024, 0, nullptr, 0, 0,
          WTa1, 1024, 0, ba1, Hb, 512, 0, BL, 512, 1024, true, 1);
    bgemm(stream, true, Hb, 512, 512, 0, nullptr, 0, 0,
          WTa2, 512, 0, ba2, Q2, 512, 0, BL, 512, 512, true, 1);
    bgemm(stream, false, Q1, 512, 512, bsQ, nullptr, 0, 0,
          Q2, 512, bsQ, nullptr, S, 256, bsS, 256, 256, 512, false, BB);

    // 5. prem side
    row_softmax_kernel<<<dim3(LL, BB), 256, 0, stream>>>(S, SP, maskH);
    bgemm(stream, true, SP, 256, 256, bsS, nullptr, 0, 0,
          VT2, 256, (long long)1024 * 256, nullptr,
          ATT, 1024, bsC, 256, 1024, 256, false, BB);
    bgemm(stream, true, P_CAT, 1024, 1024, 0, ATT, 1024, 0,
          WTc1, 2048, 0, bc1, Hb, 512, 0, BL, 512, 2048, true, 1);
    bgemm(stream, true, Hb, 512, 512, 0, nullptr, 0, 0,
          WTc2, 512, 0, bc2, Q1, 512, 0, BL, 512, 512, true, 1);

    // 6. hypo side
    col_softmax_kernel<<<dim3(LL, BB), 256, 0, stream>>>(S, SP, maskP);
    bgemm(stream, true, SP, 256, 256, bsS, nullptr, 0, 0,
          VT1, 256, (long long)1024 * 256, nullptr,
          ATT, 1024, bsC, 256, 1024, 256, false, BB);
    bgemm(stream, true, H_CAT, 1024, 1024, 0, ATT, 1024, 0,
          WTc1, 2048, 0, bc1, Hb, 512, 0, BL, 512, 2048, true, 1);
    bgemm(stream, true, Hb, 512, 512, 0, nullptr, 0, 0,
          WTc2, 512, 0, bc2, Q2, 512, 0, BL, 512, 512, true, 1);

    // 7. masked position-sum (fp32) -> R32 [64,1024]
    masked_reduce_kernel<<<dim3(2, BB), 256, 0, stream>>>(Q1, maskP, R32, 0);
    masked_reduce_kernel<<<dim3(2, BB), 256, 0, stream>>>(Q2, maskH, R32, 512);

    // 8. aggregate MLP (fp32, parallel) + output
    mlp_par_kernel<<<dim3(8, BB), 256, 0, stream>>>(R32, Wg1, bg1, H64, 1024);
    mlp_par_kernel<<<dim3(8, BB), 256, 0, stream>>>(H64, Wg2, bg2, G, 512);
    out_kernel<<<48, 256, 0, stream>>>(G, Wo, out);
}

// Round 4
// 818.779 us; speedup vs baseline: 4.2716x; 1.0766x over previous
//
#include <hip/hip_runtime.h>
#include <math.h>

#define BB   64
#define LL   256
#define EE   512
#define DD   512
#define BL   (BB * LL)      // 16384
#define BL2  (2 * BL)       // 32768 (prem rows then hypo rows)
#define MAX_DIST 11

typedef __attribute__((ext_vector_type(8))) short bf16x8;
typedef __attribute__((ext_vector_type(4))) float f32x4;

__device__ __forceinline__ float bf2f(unsigned short u) {
    union { unsigned int u; float f; } v; v.u = ((unsigned int)u) << 16; return v.f;
}
__device__ __forceinline__ unsigned short f2bf(float f) {
    union { float f; unsigned int u; } v; v.f = f;
    unsigned int r = v.u + 0x7FFF + ((v.u >> 16) & 1);   // RNE
    return (unsigned short)(r >> 16);
}

#define GLOAD16(g, l)                                                          \
    __builtin_amdgcn_global_load_lds(                                          \
        (const __attribute__((address_space(1))) void*)(g),                    \
        (__attribute__((address_space(3))) void*)(l), 16, 0, 0)

// ---------------------------------------------------------------------------
// bf16 MFMA GEMM (m97 structure + bank-conflict swizzle):
//   C = act( [A0|A1] * B^T + bias )
//   A row-major [M, K0+K1] bf16; B row-major [N, K] bf16; C bf16/fp32.
//   M, N multiples of 128; K, K0 multiples of 32.
//   LDS layout: 16B chunk (row, kchunk) stored at slot kchunk ^ ((row>>1)&3)
//   -> wave fragment reads hit all 8 bank-groups (2-way = free, m136).
// ---------------------------------------------------------------------------
template <bool OBF16>
__global__ __launch_bounds__(256) void bgemm_kernel(
    const unsigned short* __restrict__ A0, int K0, int lda0, long long bsA0,
    const unsigned short* __restrict__ A1, int lda1, long long bsA1,
    const unsigned short* __restrict__ B, int ldb, long long bsB,
    const float* __restrict__ bias,
    void* __restrict__ Cv, int ldc, long long bsC,
    int K, int relu)
{
    __shared__ unsigned short As[128 * 32];
    __shared__ unsigned short Bs[128 * 32];

    const int tid  = threadIdx.x;
    const int wave = tid >> 6;
    const int lane = tid & 63;
    const int quad = lane >> 4;
    const int l15  = lane & 15;
    const int wm   = (wave >> 1) * 64;
    const int wn   = (wave & 1) * 64;
    const int row0 = blockIdx.y * 128;
    const int col0 = blockIdx.x * 128;
    const int b    = blockIdx.z;

    const unsigned short* A0b = A0 + (long long)b * bsA0;
    const unsigned short* A1b = A1 ? (A1 + (long long)b * bsA1) : nullptr;
    const unsigned short* Bb  = B + (long long)b * bsB;

    f32x4 acc[4][4];
#pragma unroll
    for (int i = 0; i < 4; ++i)
#pragma unroll
        for (int j = 0; j < 4; ++j)
            acc[i][j] = (f32x4){0.f, 0.f, 0.f, 0.f};

    for (int kk = 0; kk < K; kk += 32) {
        const unsigned short* Ap; int lda, kloc;
        if (kk < K0) { Ap = A0b; lda = lda0; kloc = kk; }
        else         { Ap = A1b; lda = lda1; kloc = kk - K0; }
#pragma unroll
        for (int it = 0; it < 2; ++it) {
            const int c   = it * 256 + tid;
            const int row = c >> 2;
            const int kch = (c & 3) ^ ((row >> 1) & 3);
            GLOAD16(Ap + (long long)(row0 + row) * lda + kloc + kch * 8,
                    (char*)As + c * 16);
        }
#pragma unroll
        for (int it = 0; it < 2; ++it) {
            const int c   = it * 256 + tid;
            const int row = c >> 2;
            const int kch = (c & 3) ^ ((row >> 1) & 3);
            GLOAD16(Bb + (long long)(col0 + row) * ldb + kk + kch * 8,
                    (char*)Bs + c * 16);
        }
        __syncthreads();

        bf16x8 fa[4], fb[4];
#pragma unroll
        for (int mi = 0; mi < 4; ++mi) {
            const int r = wm + mi * 16 + l15;
            fa[mi] = *(const bf16x8*)&As[r * 32 + ((quad ^ ((r >> 1) & 3)) << 3)];
        }
#pragma unroll
        for (int ni = 0; ni < 4; ++ni) {
            const int r = wn + ni * 16 + l15;
            fb[ni] = *(const bf16x8*)&Bs[r * 32 + ((quad ^ ((r >> 1) & 3)) << 3)];
        }
#pragma unroll
        for (int mi = 0; mi < 4; ++mi)
#pragma unroll
            for (int ni = 0; ni < 4; ++ni)
                acc[mi][ni] = __builtin_amdgcn_mfma_f32_16x16x32_bf16(
                    fa[mi], fb[ni], acc[mi][ni], 0, 0, 0);
        __syncthreads();
    }

#pragma unroll
    for (int mi = 0; mi < 4; ++mi)
#pragma unroll
        for (int ni = 0; ni < 4; ++ni) {
            const int colb = col0 + wn + ni * 16 + l15;
            float bv = bias ? bias[colb] : 0.f;
#pragma unroll
            for (int r = 0; r < 4; ++r) {
                const int row = row0 + wm + mi * 16 + quad * 4 + r;
                float x = acc[mi][ni][r] + bv;
                if (relu) x = fmaxf(x, 0.f);
                long long off = (long long)b * bsC + (long long)row * ldc + colb;
                if (OBF16) ((unsigned short*)Cv)[off] = f2bf(x);
                else       ((float*)Cv)[off] = x;
            }
        }
}

// ---------------------------------------------------------------------------
// All-6 weight convert+transpose: W fp32 [K,512] -> WT bf16 [512,K]
// grid (16, 64, 6); early-out past each K.
// ---------------------------------------------------------------------------
struct WC6 {
    const float* s[6];
    unsigned short* d[6];
    int K[6];
};
__global__ void wconv6_kernel(WC6 wc)
{
    const int z = blockIdx.z;
    const int K = wc.K[z];
    const int k0 = blockIdx.y * 32;
    if (k0 >= K) return;
    const float* src = wc.s[z];
    unsigned short* dst = wc.d[z];
    __shared__ float tile[32][33];
    const int n0 = blockIdx.x * 32;
#pragma unroll
    for (int i = 0; i < 4; ++i)
        tile[threadIdx.y + i * 8][threadIdx.x] =
            src[(long long)(k0 + threadIdx.y + i * 8) * 512 + n0 + threadIdx.x];
    __syncthreads();
#pragma unroll
    for (int i = 0; i < 4; ++i)
        dst[(long long)(n0 + threadIdx.y + i * 8) * K + k0 + threadIdx.x] =
            f2bf(tile[threadIdx.x][threadIdx.y + i * 8]);
}

// Per-batch bf16 transpose: src batch (bz^bxor) rows [256][lds_] cols c0..C
//   -> dst[bz][c][l].  block (32,8), grid (C/32, 8, nbatch)
__global__ void btrans_kernel(const unsigned short* __restrict__ src, int lds_,
                              unsigned short* __restrict__ dst, int C, int bxor)
{
    __shared__ unsigned short tile[32][33];
    const int bz = blockIdx.z;
    const int bs = bz ^ bxor;
    const int c0 = blockIdx.x * 32, l0 = blockIdx.y * 32;
    const unsigned short* s = src + (long long)bs * 256 * lds_;
    unsigned short* d = dst + (long long)bz * C * 256;
#pragma unroll
    for (int i = 0; i < 4; ++i)
        tile[threadIdx.y + i * 8][threadIdx.x] =
            s[(long long)(l0 + threadIdx.y + i * 8) * lds_ + c0 + threadIdx.x];
    __syncthreads();
#pragma unroll
    for (int i = 0; i < 4; ++i)
        d[(long long)(c0 + threadIdx.y + i * 8) * 256 + l0 + threadIdx.x] =
            tile[threadIdx.x][threadIdx.y + i * 8];
}

// Embedding gather (both sentences) + mask -> bf16 cols [0,512) of CAT
// grid 2*BL, 128 threads
__global__ void embed_kernel(const int* __restrict__ prem_tok,
                             const int* __restrict__ hypo_tok,
                             const float* __restrict__ W,
                             unsigned short* __restrict__ cat,
                             float* __restrict__ mask)
{
    const int row = blockIdx.x;
    const int t   = threadIdx.x;
    const int tok = row < BL ? prem_tok[row] : hypo_tok[row - BL];
    if (t == 0) mask[row] = (tok != 0) ? 1.0f : 0.0f;
    float4 v = ((const float4*)(W + (long long)tok * EE))[t];
    ushort4 o;
    o.x = f2bf(v.x); o.y = f2bf(v.y); o.z = f2bf(v.z); o.w = f2bf(v.w);
    ((ushort4*)(cat + (long long)row * 1024))[t] = o;
}

// ---------------------------------------------------------------------------
// Softmax kernels (fp32 scores in, bf16 probs out), block 256
// ---------------------------------------------------------------------------
__device__ __forceinline__ float block_max(float v, float* red, int tid)
{
    red[tid] = v; __syncthreads();
    for (int st = 128; st > 0; st >>= 1) {
        if (tid < st) red[tid] = fmaxf(red[tid], red[tid + st]);
        __syncthreads();
    }
    float r = red[0]; __syncthreads();
    return r;
}
__device__ __forceinline__ float block_sum(float v, float* red, int tid)
{
    red[tid] = v; __syncthreads();
    for (int st = 128; st > 0; st >>= 1) {
        if (tid < st) red[tid] += red[tid + st];
        __syncthreads();
    }
    float r = red[0]; __syncthreads();
    return r;
}

// batch = 128 (prem 0..63, hypo 64..127), combined MASK
__global__ void self_softmax_kernel(const float* __restrict__ S,
                                    unsigned short* __restrict__ SP,
                                    const float* __restrict__ mask,
                                    const float* __restrict__ distW)
{
    __shared__ float red[256];
    const int q = blockIdx.x, b = blockIdx.y, j = threadIdx.x;
    float s = S[((long long)b * LL + q) * LL + j];
    int d = j - q;
    d = d > MAX_DIST ? MAX_DIST : (d < -MAX_DIST ? -MAX_DIST : d);
    s += distW[d + MAX_DIST];
    if (j == q) s = -INFINITY;
    if (mask[b * LL + j] == 0.0f) s = -1e9f;
    float mx = block_max(s, red, j);
    float e  = expf(s - mx);
    float sm = block_sum(e, red, j);
    SP[((long long)b * LL + q) * LL + j] = f2bf(e / sm);
}

__global__ void row_softmax_kernel(const float* __restrict__ Z,
                                   unsigned short* __restrict__ SP,
                                   const float* __restrict__ maskK)
{
    __shared__ float red[256];
    const int p = blockIdx.x, b = blockIdx.y, j = threadIdx.x;
    float s = Z[((long long)b * LL + p) * LL + j];
    if (maskK[b * LL + j] == 0.0f) s = -1e9f;
    float mx = block_max(s, red, j);
    float e  = expf(s - mx);
    float sm = block_sum(e, red, j);
    SP[((long long)b * LL + p) * LL + j] = f2bf(e / sm);
}

// col softmax over p, output transposed: SP[b][h][p]
__global__ void col_softmax_kernel(const float* __restrict__ Z,
                                   unsigned short* __restrict__ SP,
                                   const float* __restrict__ maskQ)
{
    __shared__ float red[256];
    const int h = blockIdx.x, b = blockIdx.y, p = threadIdx.x;
    float s = Z[((long long)b * LL + p) * LL + h];
    if (maskQ[b * LL + p] == 0.0f) s = -1e9f;
    float mx = block_max(s, red, p);
    float e  = expf(s - mx);
    float sm = block_sum(e, red, p);
    SP[((long long)b * LL + h) * LL + p] = f2bf(e / sm);
}

// Masked position-sum, both sides: grid (4, 64), block 256.
//   x-blocks 0,1 -> prem (Q rows 0..BL) -> R cols 0..511
//   x-blocks 2,3 -> hypo (Q rows BL..)  -> R cols 512..1023
__global__ void masked_reduce_kernel(const unsigned short* __restrict__ Q,
                                     const float* __restrict__ MASK,
                                     float* __restrict__ R32)
{
    const int side = blockIdx.x >> 1;
    const int c    = (blockIdx.x & 1) * 256 + threadIdx.x;
    const int b    = blockIdx.y;
    const unsigned short* xb = Q + ((long long)(side * BL + b * LL)) * DD + c;
    const float* mb = MASK + side * BL + b * LL;
    float a0 = 0.f, a1 = 0.f, a2 = 0.f, a3 = 0.f;
#pragma unroll 4
    for (int r = 0; r < 64; ++r) {
        a0 = fmaf(bf2f(xb[(r       ) * DD]), mb[r      ], a0);
        a1 = fmaf(bf2f(xb[(r +  64) * DD]), mb[r +  64], a1);
        a2 = fmaf(bf2f(xb[(r + 128) * DD]), mb[r + 128], a2);
        a3 = fmaf(bf2f(xb[(r + 192) * DD]), mb[r + 192], a3);
    }
    R32[b * 1024 + side * 512 + c] = (a0 + a1) + (a2 + a3);
}

// Parallel small fp32 MLP layer: grid (8, BB), block 256
__global__ __launch_bounds__(256) void mlp_par_kernel(
    const float* __restrict__ X, const float* __restrict__ W,
    const float* __restrict__ bias, float* __restrict__ Y, int Kin)
{
    __shared__ float red[4][64];
    const int b  = blockIdx.y;
    const int n  = blockIdx.x * 64 + (threadIdx.x & 63);
    const int ts = threadIdx.x >> 6;
    const int kc = Kin >> 2;
    const float* x = X + (long long)b * Kin + ts * kc;
    const float* w = W + (long long)(ts * kc) * 512 + n;
    float a0 = 0.f, a1 = 0.f;
#pragma unroll 8
    for (int k = 0; k < kc; k += 2) {
        a0 = fmaf(x[k],     w[(long long)k * 512],       a0);
        a1 = fmaf(x[k + 1], w[(long long)(k + 1) * 512], a1);
    }
    red[ts][threadIdx.x & 63] = a0 + a1;
    __syncthreads();
    if (ts == 0) {
        float v = red[0][threadIdx.x] + red[1][threadIdx.x] +
                  red[2][threadIdx.x] + red[3][threadIdx.x] + bias[n];
        Y[b * 512 + n] = fmaxf(v, 0.f);
    }
}

// Final output: one wave per (b,o).  grid 48 x 256 thr = 192 waves.
__global__ void out_kernel(const float* __restrict__ G,
                           const float* __restrict__ Wo,
                           float* __restrict__ out)
{
    const int wid  = blockIdx.x * 4 + (threadIdx.x >> 6);
    const int lane = threadIdx.x & 63;
    const int b = wid / 3, o = wid % 3;
    float acc = 0.f;
#pragma unroll
    for (int j = 0; j < 8; ++j) {
        int d = lane + j * 64;
        acc = fmaf(G[b * DD + d], Wo[d * 3 + o], acc);
    }
#pragma unroll
    for (int st = 32; st > 0; st >>= 1)
        acc += __shfl_down(acc, st, 64);
    if (lane == 0) out[wid] = acc;
}

// ---------------------------------------------------------------------------
// Host-side launcher
// ---------------------------------------------------------------------------
static inline void bgemm(hipStream_t stream, bool obf16,
                         const unsigned short* A0, int K0, int lda0, long long bsA0,
                         const unsigned short* A1, int lda1, long long bsA1,
                         const unsigned short* B, int ldb, long long bsB,
                         const float* bias,
                         void* C, int ldc, long long bsC,
                         int M, int N, int K, bool relu, int batch)
{
    dim3 grid(N / 128, M / 128, batch);
    if (obf16)
        bgemm_kernel<true><<<grid, 256, 0, stream>>>(A0, K0, lda0, bsA0, A1, lda1, bsA1,
                                                     B, ldb, bsB, bias, C, ldc, bsC, K, relu);
    else
        bgemm_kernel<false><<<grid, 256, 0, stream>>>(A0, K0, lda0, bsA0, A1, lda1, bsA1,
                                                      B, ldb, bsB, bias, C, ldc, bsC, K, relu);
}

extern "C" void kernel_launch(void* const* d_in, const int* in_sizes, int n_in,
                              void* d_out, int out_size, void* d_ws, size_t ws_size,
                              hipStream_t stream)
{
    (void)in_sizes; (void)n_in; (void)out_size; (void)ws_size;

    const int*   prem_tok = (const int*)d_in[0];
    const int*   hypo_tok = (const int*)d_in[1];
    const float* embW = (const float*)d_in[2];
    const float* dW   = (const float*)d_in[3];
    const float* Ws1  = (const float*)d_in[4];
    const float* bs1  = (const float*)d_in[5];
    const float* Ws2  = (const float*)d_in[6];
    const float* bs2  = (const float*)d_in[7];
    const float* Wa1  = (const float*)d_in[8];
    const float* ba1  = (const float*)d_in[9];
    const float* Wa2  = (const float*)d_in[10];
    const float* ba2  = (const float*)d_in[11];
    const float* Wc1  = (const float*)d_in[12];
    const float* bc1  = (const float*)d_in[13];
    const float* Wc2  = (const float*)d_in[14];
    const float* bc2  = (const float*)d_in[15];
    const float* Wg1  = (const float*)d_in[16];
    const float* bg1  = (const float*)d_in[17];
    const float* Wg2  = (const float*)d_in[18];
    const float* bg2  = (const float*)d_in[19];
    const float* Wo   = (const float*)d_in[20];
    float* out = (float*)d_out;

    // ---- workspace carve-up (bytes), ~324 MB ----
    char* ws = (char*)d_ws;
    size_t off = 0;
    auto alloc = [&](size_t bytes) {
        char* p = ws + off; off += (bytes + 255) & ~(size_t)255; return p;
    };
    unsigned short* CAT  = (unsigned short*)alloc((size_t)BL2 * 1024 * 2); // 67 MB
    unsigned short* VTF  = (unsigned short*)alloc((size_t)128 * 1024 * 256 * 2); // 67 MB
    unsigned short* Hb   = (unsigned short*)alloc((size_t)BL2 * 512 * 2);  // 33.6
    unsigned short* Q    = (unsigned short*)alloc((size_t)BL2 * 512 * 2);  // 33.6
    unsigned short* ATT  = (unsigned short*)alloc((size_t)BL2 * 1024 * 2); // 67 MB
    float*          S    = (float*)alloc((size_t)128 * LL * LL * 4);       // 33.5
    unsigned short* SP   = (unsigned short*)alloc((size_t)128 * LL * LL * 2); // 16.8
    float*          MASK = (float*)alloc((size_t)BL2 * 4);
    float*          R32  = (float*)alloc((size_t)BB * 1024 * 4);
    float*          H64  = (float*)alloc((size_t)BB * 512 * 4);
    float*          G    = (float*)alloc((size_t)BB * 512 * 4);
    unsigned short* WTs1 = (unsigned short*)alloc((size_t)512 * 512 * 2);
    unsigned short* WTs2 = (unsigned short*)alloc((size_t)512 * 512 * 2);
    unsigned short* WTa1 = (unsigned short*)alloc((size_t)1024 * 512 * 2);
    unsigned short* WTa2 = (unsigned short*)alloc((size_t)512 * 512 * 2);
    unsigned short* WTc1 = (unsigned short*)alloc((size_t)2048 * 512 * 2);
    unsigned short* WTc2 = (unsigned short*)alloc((size_t)512 * 512 * 2);

    const long long bsQ = (long long)LL * DD;       // 131072
    const long long bsS = (long long)LL * LL;       // 65536
    const long long bsC = (long long)LL * 1024;     // 262144

    dim3 tb(32, 8);

    // 0. all weights: convert + transpose to [512, K] bf16, one dispatch
    WC6 wc;
    wc.s[0] = Ws1; wc.d[0] = WTs1; wc.K[0] = 512;
    wc.s[1] = Ws2; wc.d[1] = WTs2; wc.K[1] = 512;
    wc.s[2] = Wa1; wc.d[2] = WTa1; wc.K[2] = 1024;
    wc.s[3] = Wa2; wc.d[3] = WTa2; wc.K[3] = 512;
    wc.s[4] = Wc1; wc.d[4] = WTc1; wc.K[4] = 2048;
    wc.s[5] = Wc2; wc.d[5] = WTc2; wc.K[5] = 512;
    wconv6_kernel<<<dim3(16, 64, 6), tb, 0, stream>>>(wc);

    // 1. embeddings + masks (both sentences)
    embed_kernel<<<BL2, 128, 0, stream>>>(prem_tok, hypo_tok, embW, CAT, MASK);

    // 2. self branch, merged (M = 32768, batch = 128)
    bgemm(stream, true, CAT, 512, 1024, 0, nullptr, 0, 0,
          WTs1, 512, 0, bs1, Hb, 512, 0, BL2, 512, 512, true, 1);
    bgemm(stream, true, Hb, 512, 512, 0, nullptr, 0, 0,
          WTs2, 512, 0, bs2, Q, 512, 0, BL2, 512, 512, true, 1);
    // x^T (cols 0..511) per batch -> VTF area as [128][512][256]
    btrans_kernel<<<dim3(16, 8, 128), tb, 0, stream>>>(CAT, 1024, VTF, 512, 0);
    // scores = q @ q^T (fp32), batch 128
    bgemm(stream, false, Q, 512, 512, bsQ, nullptr, 0, 0,
          Q, 512, bsQ, nullptr, S, 256, bsS, 256, 256, 512, false, 128);
    self_softmax_kernel<<<dim3(LL, 128), 256, 0, stream>>>(S, SP, MASK, dW);
    // ctx = att @ x -> CAT cols [512,1024), batch 128
    bgemm(stream, true, SP, 256, 256, bsS, nullptr, 0, 0,
          VTF, 256, (long long)512 * 256, nullptr,
          CAT + 512, 1024, bsC, 256, 512, 256, false, 128);

    // 3. full V^T, cross-ordered (batch z holds sentence z^64)
    btrans_kernel<<<dim3(32, 8, 128), tb, 0, stream>>>(CAT, 1024, VTF, 1024, 64);

    // 4. inter-attention projections (merged M = 32768)
    bgemm(stream, true, CAT, 1024, 1024, 0, nullptr, 0, 0,
          WTa1, 1024, 0, ba1, Hb, 512, 0, BL2, 512, 1024, true, 1);
    bgemm(stream, true, Hb, 512, 512, 0, nullptr, 0, 0,
          WTa2, 512, 0, ba2, Q, 512, 0, BL2, 512, 512, true, 1);
    // z = pq @ hk^T (fp32), batch 64
    bgemm(stream, false, Q, 512, 512, bsQ, nullptr, 0, 0,
          Q + (long long)BL * 512, 512, bsQ, nullptr,
          S, 256, bsS, 256, 256, 512, false, 64);

    // 5. both softmaxes, then one merged attend (batch 128)
    row_softmax_kernel<<<dim3(LL, 64), 256, 0, stream>>>(S, SP, MASK + BL);
    col_softmax_kernel<<<dim3(LL, 64), 256, 0, stream>>>(S, SP + 64 * bsS, MASK);
    bgemm(stream, true, SP, 256, 256, bsS, nullptr, 0, 0,
          VTF, 256, (long long)1024 * 256, nullptr,
          ATT, 1024, bsC, 256, 1024, 256, false, 128);

    // 6. compare MLP, merged (M = 32768, K = 2048 via concat)
    bgemm(stream, true, CAT, 1024, 1024, 0, ATT, 1024, 0,
          WTc1, 2048, 0, bc1, Hb, 512, 0, BL2, 512, 2048, true, 1);
    bgemm(stream, true, Hb, 512, 512, 0, nullptr, 0, 0,
          WTc2, 512, 0, bc2, Q, 512, 0, BL2, 512, 512, true, 1);

    // 7. masked position-sum (both sides) -> R32 [64, 1024]
    masked_reduce_kernel<<<dim3(4, BB), 256, 0, stream>>>(Q, MASK, R32);

    // 8. aggregate MLP (fp32) + output
    mlp_par_kernel<<<dim3(8, BB), 256, 0, stream>>>(R32, Wg1, bg1, H64, 1024);
    mlp_par_kernel<<<dim3(8, BB), 256, 0, stream>>>(H64, Wg2, bg2, G, 512);
    out_kernel<<<48, 256, 0, stream>>>(G, Wo, out);
}

// Round 5
// 776.936 us; speedup vs baseline: 4.5017x; 1.0539x over previous
//
#include <hip/hip_runtime.h>
#include <math.h>

#define BB   64
#define LL   256
#define EE   512
#define DD   512
#define BL   (BB * LL)      // 16384
#define BL2  (2 * BL)       // 32768 (prem rows then hypo rows)
#define MAX_DIST 11

typedef __attribute__((ext_vector_type(8))) short bf16x8;
typedef __attribute__((ext_vector_type(8))) unsigned short u16x8;
typedef __attribute__((ext_vector_type(4))) float f32x4;

__device__ __forceinline__ float bf2f(unsigned short u) {
    union { unsigned int u; float f; } v; v.u = ((unsigned int)u) << 16; return v.f;
}
__device__ __forceinline__ unsigned short f2bf(float f) {
    union { float f; unsigned int u; } v; v.f = f;
    unsigned int r = v.u + 0x7FFF + ((v.u >> 16) & 1);   // RNE
    return (unsigned short)(r >> 16);
}

#define GLOAD16(g, l)                                                          \
    __builtin_amdgcn_global_load_lds(                                          \
        (const __attribute__((address_space(1))) void*)(g),                    \
        (__attribute__((address_space(3))) void*)(l), 16, 0, 0)

// ---------------------------------------------------------------------------
// bf16 MFMA GEMM, BK=64:  C = act( [A0|A1] * B^T + bias )
//   A row-major [M, K0+K1] bf16; B row-major [N, K] bf16; C bf16/fp32.
//   M, N multiples of 128; K, K0 multiples of 64.
//   LDS rows of 64 bf16 (8 x 16B chunks); chunk g of row r stored at slot
//   g ^ (r & 7)  -> staging keeps wave-uniform-base+lane*16, fragment reads
//   spread all 8 dword-phases (2 lanes each = free, m136).
//   BK=64 halves barrier count vs BK=32 (barrier drain was ~50% of cycles);
//   32 KB LDS keeps occupancy VGPR-bound (~3 blocks/CU), unlike BK=128 (m132).
// ---------------------------------------------------------------------------
template <bool OBF16>
__global__ __launch_bounds__(256) void bgemm_kernel(
    const unsigned short* __restrict__ A0, int K0, int lda0, long long bsA0,
    const unsigned short* __restrict__ A1, int lda1, long long bsA1,
    const unsigned short* __restrict__ B, int ldb, long long bsB,
    const float* __restrict__ bias,
    void* __restrict__ Cv, int ldc, long long bsC,
    int K, int relu)
{
    __shared__ unsigned short smem[16384];    // 32 KB: As 16 KB | Bs 16 KB
    unsigned short* As = smem;
    unsigned short* Bs = smem + 8192;

    const int tid  = threadIdx.x;
    const int wave = tid >> 6;
    const int lane = tid & 63;
    const int quad = lane >> 4;
    const int l15  = lane & 15;
    const int wm   = (wave >> 1) * 64;
    const int wn   = (wave & 1) * 64;
    const int row0 = blockIdx.y * 128;
    const int col0 = blockIdx.x * 128;
    const int b    = blockIdx.z;

    const unsigned short* A0b = A0 + (long long)b * bsA0;
    const unsigned short* A1b = A1 ? (A1 + (long long)b * bsA1) : nullptr;
    const unsigned short* Bb  = B + (long long)b * bsB;

    f32x4 acc[4][4];
#pragma unroll
    for (int i = 0; i < 4; ++i)
#pragma unroll
        for (int j = 0; j < 4; ++j)
            acc[i][j] = (f32x4){0.f, 0.f, 0.f, 0.f};

    for (int kk = 0; kk < K; kk += 64) {
        const unsigned short* Ap; int lda, kloc;
        if (kk < K0) { Ap = A0b; lda = lda0; kloc = kk; }
        else         { Ap = A1b; lda = lda1; kloc = kk - K0; }
        // stage A: 128 rows x 64 k = 1024 chunks of 16B, 4 per thread
#pragma unroll
        for (int it = 0; it < 4; ++it) {
            const int c   = it * 256 + tid;
            const int row = c >> 3;
            const int kch = (c & 7) ^ (row & 7);
            GLOAD16(Ap + (long long)(row0 + row) * lda + kloc + kch * 8,
                    (char*)As + c * 16);
        }
#pragma unroll
        for (int it = 0; it < 4; ++it) {
            const int c   = it * 256 + tid;
            const int row = c >> 3;
            const int kch = (c & 7) ^ (row & 7);
            GLOAD16(Bb + (long long)(col0 + row) * ldb + kk + kch * 8,
                    (char*)Bs + c * 16);
        }
        __syncthreads();

#pragma unroll
        for (int s = 0; s < 2; ++s) {
            bf16x8 fa[4], fb[4];
#pragma unroll
            for (int mi = 0; mi < 4; ++mi) {
                const int r = wm + mi * 16 + l15;
                const int slot = (s * 4 + quad) ^ (r & 7);
                fa[mi] = *(const bf16x8*)&As[(r * 8 + slot) * 8];
            }
#pragma unroll
            for (int ni = 0; ni < 4; ++ni) {
                const int r = wn + ni * 16 + l15;
                const int slot = (s * 4 + quad) ^ (r & 7);
                fb[ni] = *(const bf16x8*)&Bs[(r * 8 + slot) * 8];
            }
#pragma unroll
            for (int mi = 0; mi < 4; ++mi)
#pragma unroll
                for (int ni = 0; ni < 4; ++ni)
                    acc[mi][ni] = __builtin_amdgcn_mfma_f32_16x16x32_bf16(
                        fa[mi], fb[ni], acc[mi][ni], 0, 0, 0);
        }
        __syncthreads();
    }

    // bias per ni (col = col0 + wn + ni*16 + l15)
    float bv4[4];
#pragma unroll
    for (int ni = 0; ni < 4; ++ni)
        bv4[ni] = bias ? bias[col0 + wn + ni * 16 + l15] : 0.f;

    if (OBF16) {
        // coalesced epilogue: 32-row slabs through LDS, 16B packed stores
        float* Ls = (float*)smem;     // [32][129] fp32 = 16512 B
        unsigned short* Cb = (unsigned short*)Cv + (long long)b * bsC;
#pragma unroll
        for (int h = 0; h < 4; ++h) {
            if ((wave >> 1) == (h >> 1)) {
                const int mi0 = (h & 1) * 2;
#pragma unroll
                for (int mm = 0; mm < 2; ++mm) {
#pragma unroll
                    for (int ni = 0; ni < 4; ++ni) {
#pragma unroll
                        for (int r = 0; r < 4; ++r) {
                            float x = acc[mi0 + mm][ni][r] + bv4[ni];
                            if (relu) x = fmaxf(x, 0.f);
                            Ls[(mm * 16 + quad * 4 + r) * 129 +
                               wn + ni * 16 + l15] = x;
                        }
                    }
                }
            }
            __syncthreads();
#pragma unroll
            for (int it = 0; it < 2; ++it) {
                const int c  = it * 256 + tid;   // 0..511
                const int lr = c >> 4;           // 0..31
                const int cc = (c & 15) * 8;
                const float* src = &Ls[lr * 129 + cc];
                u16x8 u;
#pragma unroll
                for (int j = 0; j < 8; ++j) u[j] = f2bf(src[j]);
                *(u16x8*)(Cb + (long long)(row0 + h * 32 + lr) * ldc +
                          col0 + cc) = u;
            }
            __syncthreads();
        }
    } else {
        float* Cb = (float*)Cv + (long long)b * bsC;
#pragma unroll
        for (int mi = 0; mi < 4; ++mi)
#pragma unroll
            for (int ni = 0; ni < 4; ++ni) {
                const int colb = col0 + wn + ni * 16 + l15;
#pragma unroll
                for (int r = 0; r < 4; ++r) {
                    const int row = row0 + wm + mi * 16 + quad * 4 + r;
                    float x = acc[mi][ni][r] + bv4[ni];
                    if (relu) x = fmaxf(x, 0.f);
                    Cb[(long long)row * ldc + colb] = x;
                }
            }
    }
}

// ---------------------------------------------------------------------------
// All-6 weight convert+transpose: W fp32 [K,512] -> WT bf16 [512,K]
// ---------------------------------------------------------------------------
struct WC6 {
    const float* s[6];
    unsigned short* d[6];
    int K[6];
};
__global__ void wconv6_kernel(WC6 wc)
{
    const int z = blockIdx.z;
    const int K = wc.K[z];
    const int k0 = blockIdx.y * 32;
    if (k0 >= K) return;
    const float* src = wc.s[z];
    unsigned short* dst = wc.d[z];
    __shared__ float tile[32][33];
    const int n0 = blockIdx.x * 32;
#pragma unroll
    for (int i = 0; i < 4; ++i)
        tile[threadIdx.y + i * 8][threadIdx.x] =
            src[(long long)(k0 + threadIdx.y + i * 8) * 512 + n0 + threadIdx.x];
    __syncthreads();
#pragma unroll
    for (int i = 0; i < 4; ++i)
        dst[(long long)(n0 + threadIdx.y + i * 8) * K + k0 + threadIdx.x] =
            f2bf(tile[threadIdx.x][threadIdx.y + i * 8]);
}

// Per-batch bf16 transpose: src batch (bz^bxor) rows [256][lds_] cols c0..C
__global__ void btrans_kernel(const unsigned short* __restrict__ src, int lds_,
                              unsigned short* __restrict__ dst, int C, int bxor)
{
    __shared__ unsigned short tile[32][33];
    const int bz = blockIdx.z;
    const int bs = bz ^ bxor;
    const int c0 = blockIdx.x * 32, l0 = blockIdx.y * 32;
    const unsigned short* s = src + (long long)bs * 256 * lds_;
    unsigned short* d = dst + (long long)bz * C * 256;
#pragma unroll
    for (int i = 0; i < 4; ++i)
        tile[threadIdx.y + i * 8][threadIdx.x] =
            s[(long long)(l0 + threadIdx.y + i * 8) * lds_ + c0 + threadIdx.x];
    __syncthreads();
#pragma unroll
    for (int i = 0; i < 4; ++i)
        d[(long long)(c0 + threadIdx.y + i * 8) * 256 + l0 + threadIdx.x] =
            tile[threadIdx.x][threadIdx.y + i * 8];
}

// Embedding gather (both sentences) + mask
__global__ void embed_kernel(const int* __restrict__ prem_tok,
                             const int* __restrict__ hypo_tok,
                             const float* __restrict__ W,
                             unsigned short* __restrict__ cat,
                             float* __restrict__ mask)
{
    const int row = blockIdx.x;
    const int t   = threadIdx.x;
    const int tok = row < BL ? prem_tok[row] : hypo_tok[row - BL];
    if (t == 0) mask[row] = (tok != 0) ? 1.0f : 0.0f;
    float4 v = ((const float4*)(W + (long long)tok * EE))[t];
    ushort4 o;
    o.x = f2bf(v.x); o.y = f2bf(v.y); o.z = f2bf(v.z); o.w = f2bf(v.w);
    ((ushort4*)(cat + (long long)row * 1024))[t] = o;
}

// ---------------------------------------------------------------------------
// Softmax kernels (fp32 scores in, bf16 probs out), block 256
// ---------------------------------------------------------------------------
__device__ __forceinline__ float block_max(float v, float* red, int tid)
{
    red[tid] = v; __syncthreads();
    for (int st = 128; st > 0; st >>= 1) {
        if (tid < st) red[tid] = fmaxf(red[tid], red[tid + st]);
        __syncthreads();
    }
    float r = red[0]; __syncthreads();
    return r;
}
__device__ __forceinline__ float block_sum(float v, float* red, int tid)
{
    red[tid] = v; __syncthreads();
    for (int st = 128; st > 0; st >>= 1) {
        if (tid < st) red[tid] += red[tid + st];
        __syncthreads();
    }
    float r = red[0]; __syncthreads();
    return r;
}

__global__ void self_softmax_kernel(const float* __restrict__ S,
                                    unsigned short* __restrict__ SP,
                                    const float* __restrict__ mask,
                                    const float* __restrict__ distW)
{
    __shared__ float red[256];
    const int q = blockIdx.x, b = blockIdx.y, j = threadIdx.x;
    float s = S[((long long)b * LL + q) * LL + j];
    int d = j - q;
    d = d > MAX_DIST ? MAX_DIST : (d < -MAX_DIST ? -MAX_DIST : d);
    s += distW[d + MAX_DIST];
    if (j == q) s = -INFINITY;
    if (mask[b * LL + j] == 0.0f) s = -1e9f;
    float mx = block_max(s, red, j);
    float e  = expf(s - mx);
    float sm = block_sum(e, red, j);
    SP[((long long)b * LL + q) * LL + j] = f2bf(e / sm);
}

__global__ void row_softmax_kernel(const float* __restrict__ Z,
                                   unsigned short* __restrict__ SP,
                                   const float* __restrict__ maskK)
{
    __shared__ float red[256];
    const int p = blockIdx.x, b = blockIdx.y, j = threadIdx.x;
    float s = Z[((long long)b * LL + p) * LL + j];
    if (maskK[b * LL + j] == 0.0f) s = -1e9f;
    float mx = block_max(s, red, j);
    float e  = expf(s - mx);
    float sm = block_sum(e, red, j);
    SP[((long long)b * LL + p) * LL + j] = f2bf(e / sm);
}

// col softmax over p, output transposed: SP[b][h][p]
__global__ void col_softmax_kernel(const float* __restrict__ Z,
                                   unsigned short* __restrict__ SP,
                                   const float* __restrict__ maskQ)
{
    __shared__ float red[256];
    const int h = blockIdx.x, b = blockIdx.y, p = threadIdx.x;
    float s = Z[((long long)b * LL + p) * LL + h];
    if (maskQ[b * LL + p] == 0.0f) s = -1e9f;
    float mx = block_max(s, red, p);
    float e  = expf(s - mx);
    float sm = block_sum(e, red, p);
    SP[((long long)b * LL + h) * LL + p] = f2bf(e / sm);
}

// Masked position-sum, both sides: grid (4, 64), block 256.
__global__ void masked_reduce_kernel(const unsigned short* __restrict__ Q,
                                     const float* __restrict__ MASK,
                                     float* __restrict__ R32)
{
    const int side = blockIdx.x >> 1;
    const int c    = (blockIdx.x & 1) * 256 + threadIdx.x;
    const int b    = blockIdx.y;
    const unsigned short* xb = Q + ((long long)(side * BL + b * LL)) * DD + c;
    const float* mb = MASK + side * BL + b * LL;
    float a0 = 0.f, a1 = 0.f, a2 = 0.f, a3 = 0.f;
#pragma unroll 4
    for (int r = 0; r < 64; ++r) {
        a0 = fmaf(bf2f(xb[(r       ) * DD]), mb[r      ], a0);
        a1 = fmaf(bf2f(xb[(r +  64) * DD]), mb[r +  64], a1);
        a2 = fmaf(bf2f(xb[(r + 128) * DD]), mb[r + 128], a2);
        a3 = fmaf(bf2f(xb[(r + 192) * DD]), mb[r + 192], a3);
    }
    R32[b * 1024 + side * 512 + c] = (a0 + a1) + (a2 + a3);
}

// Parallel small fp32 MLP layer: grid (8, BB), block 256
__global__ __launch_bounds__(256) void mlp_par_kernel(
    const float* __restrict__ X, const float* __restrict__ W,
    const float* __restrict__ bias, float* __restrict__ Y, int Kin)
{
    __shared__ float red[4][64];
    const int b  = blockIdx.y;
    const int n  = blockIdx.x * 64 + (threadIdx.x & 63);
    const int ts = threadIdx.x >> 6;
    const int kc = Kin >> 2;
    const float* x = X + (long long)b * Kin + ts * kc;
    const float* w = W + (long long)(ts * kc) * 512 + n;
    float a0 = 0.f, a1 = 0.f;
#pragma unroll 8
    for (int k = 0; k < kc; k += 2) {
        a0 = fmaf(x[k],     w[(long long)k * 512],       a0);
        a1 = fmaf(x[k + 1], w[(long long)(k + 1) * 512], a1);
    }
    red[ts][threadIdx.x & 63] = a0 + a1;
    __syncthreads();
    if (ts == 0) {
        float v = red[0][threadIdx.x] + red[1][threadIdx.x] +
                  red[2][threadIdx.x] + red[3][threadIdx.x] + bias[n];
        Y[b * 512 + n] = fmaxf(v, 0.f);
    }
}

// Final output: one wave per (b,o).  grid 48 x 256 thr = 192 waves.
__global__ void out_kernel(const float* __restrict__ G,
                           const float* __restrict__ Wo,
                           float* __restrict__ out)
{
    const int wid  = blockIdx.x * 4 + (threadIdx.x >> 6);
    const int lane = threadIdx.x & 63;
    const int b = wid / 3, o = wid % 3;
    float acc = 0.f;
#pragma unroll
    for (int j = 0; j < 8; ++j) {
        int d = lane + j * 64;
        acc = fmaf(G[b * DD + d], Wo[d * 3 + o], acc);
    }
#pragma unroll
    for (int st = 32; st > 0; st >>= 1)
        acc += __shfl_down(acc, st, 64);
    if (lane == 0) out[wid] = acc;
}

// ---------------------------------------------------------------------------
// Host-side launcher
// ---------------------------------------------------------------------------
static inline void bgemm(hipStream_t stream, bool obf16,
                         const unsigned short* A0, int K0, int lda0, long long bsA0,
                         const unsigned short* A1, int lda1, long long bsA1,
                         const unsigned short* B, int ldb, long long bsB,
                         const float* bias,
                         void* C, int ldc, long long bsC,
                         int M, int N, int K, bool relu, int batch)
{
    dim3 grid(N / 128, M / 128, batch);
    if (obf16)
        bgemm_kernel<true><<<grid, 256, 0, stream>>>(A0, K0, lda0, bsA0, A1, lda1, bsA1,
                                                     B, ldb, bsB, bias, C, ldc, bsC, K, relu);
    else
        bgemm_kernel<false><<<grid, 256, 0, stream>>>(A0, K0, lda0, bsA0, A1, lda1, bsA1,
                                                      B, ldb, bsB, bias, C, ldc, bsC, K, relu);
}

extern "C" void kernel_launch(void* const* d_in, const int* in_sizes, int n_in,
                              void* d_out, int out_size, void* d_ws, size_t ws_size,
                              hipStream_t stream)
{
    (void)in_sizes; (void)n_in; (void)out_size; (void)ws_size;

    const int*   prem_tok = (const int*)d_in[0];
    const int*   hypo_tok = (const int*)d_in[1];
    const float* embW = (const float*)d_in[2];
    const float* dW   = (const float*)d_in[3];
    const float* Ws1  = (const float*)d_in[4];
    const float* bs1  = (const float*)d_in[5];
    const float* Ws2  = (const float*)d_in[6];
    const float* bs2  = (const float*)d_in[7];
    const float* Wa1  = (const float*)d_in[8];
    const float* ba1  = (const float*)d_in[9];
    const float* Wa2  = (const float*)d_in[10];
    const float* ba2  = (const float*)d_in[11];
    const float* Wc1  = (const float*)d_in[12];
    const float* bc1  = (const float*)d_in[13];
    const float* Wc2  = (const float*)d_in[14];
    const float* bc2  = (const float*)d_in[15];
    const float* Wg1  = (const float*)d_in[16];
    const float* bg1  = (const float*)d_in[17];
    const float* Wg2  = (const float*)d_in[18];
    const float* bg2  = (const float*)d_in[19];
    const float* Wo   = (const float*)d_in[20];
    float* out = (float*)d_out;

    // ---- workspace carve-up (bytes), ~324 MB ----
    char* ws = (char*)d_ws;
    size_t off = 0;
    auto alloc = [&](size_t bytes) {
        char* p = ws + off; off += (bytes + 255) & ~(size_t)255; return p;
    };
    unsigned short* CAT  = (unsigned short*)alloc((size_t)BL2 * 1024 * 2);
    unsigned short* VTF  = (unsigned short*)alloc((size_t)128 * 1024 * 256 * 2);
    unsigned short* Hb   = (unsigned short*)alloc((size_t)BL2 * 512 * 2);
    unsigned short* Q    = (unsigned short*)alloc((size_t)BL2 * 512 * 2);
    unsigned short* ATT  = (unsigned short*)alloc((size_t)BL2 * 1024 * 2);
    float*          S    = (float*)alloc((size_t)128 * LL * LL * 4);
    unsigned short* SP   = (unsigned short*)alloc((size_t)128 * LL * LL * 2);
    float*          MASK = (float*)alloc((size_t)BL2 * 4);
    float*          R32  = (float*)alloc((size_t)BB * 1024 * 4);
    float*          H64  = (float*)alloc((size_t)BB * 512 * 4);
    float*          G    = (float*)alloc((size_t)BB * 512 * 4);
    unsigned short* WTs1 = (unsigned short*)alloc((size_t)512 * 512 * 2);
    unsigned short* WTs2 = (unsigned short*)alloc((size_t)512 * 512 * 2);
    unsigned short* WTa1 = (unsigned short*)alloc((size_t)1024 * 512 * 2);
    unsigned short* WTa2 = (unsigned short*)alloc((size_t)512 * 512 * 2);
    unsigned short* WTc1 = (unsigned short*)alloc((size_t)2048 * 512 * 2);
    unsigned short* WTc2 = (unsigned short*)alloc((size_t)512 * 512 * 2);

    const long long bsQ = (long long)LL * DD;       // 131072
    const long long bsS = (long long)LL * LL;       // 65536
    const long long bsC = (long long)LL * 1024;     // 262144

    dim3 tb(32, 8);

    // 0. all weights: convert + transpose to [512, K] bf16, one dispatch
    WC6 wc;
    wc.s[0] = Ws1; wc.d[0] = WTs1; wc.K[0] = 512;
    wc.s[1] = Ws2; wc.d[1] = WTs2; wc.K[1] = 512;
    wc.s[2] = Wa1; wc.d[2] = WTa1; wc.K[2] = 1024;
    wc.s[3] = Wa2; wc.d[3] = WTa2; wc.K[3] = 512;
    wc.s[4] = Wc1; wc.d[4] = WTc1; wc.K[4] = 2048;
    wc.s[5] = Wc2; wc.d[5] = WTc2; wc.K[5] = 512;
    wconv6_kernel<<<dim3(16, 64, 6), tb, 0, stream>>>(wc);

    // 1. embeddings + masks (both sentences)
    embed_kernel<<<BL2, 128, 0, stream>>>(prem_tok, hypo_tok, embW, CAT, MASK);

    // 2. self branch, merged (M = 32768, batch = 128)
    bgemm(stream, true, CAT, 512, 1024, 0, nullptr, 0, 0,
          WTs1, 512, 0, bs1, Hb, 512, 0, BL2, 512, 512, true, 1);
    bgemm(stream, true, Hb, 512, 512, 0, nullptr, 0, 0,
          WTs2, 512, 0, bs2, Q, 512, 0, BL2, 512, 512, true, 1);
    btrans_kernel<<<dim3(16, 8, 128), tb, 0, stream>>>(CAT, 1024, VTF, 512, 0);
    bgemm(stream, false, Q, 512, 512, bsQ, nullptr, 0, 0,
          Q, 512, bsQ, nullptr, S, 256, bsS, 256, 256, 512, false, 128);
    self_softmax_kernel<<<dim3(LL, 128), 256, 0, stream>>>(S, SP, MASK, dW);
    bgemm(stream, true, SP, 256, 256, bsS, nullptr, 0, 0,
          VTF, 256, (long long)512 * 256, nullptr,
          CAT + 512, 1024, bsC, 256, 512, 256, false, 128);

    // 3. full V^T, cross-ordered (batch z holds sentence z^64)
    btrans_kernel<<<dim3(32, 8, 128), tb, 0, stream>>>(CAT, 1024, VTF, 1024, 64);

    // 4. inter-attention projections (merged M = 32768)
    bgemm(stream, true, CAT, 1024, 1024, 0, nullptr, 0, 0,
          WTa1, 1024, 0, ba1, Hb, 512, 0, BL2, 512, 1024, true, 1);
    bgemm(stream, true, Hb, 512, 512, 0, nullptr, 0, 0,
          WTa2, 512, 0, ba2, Q, 512, 0, BL2, 512, 512, true, 1);
    bgemm(stream, false, Q, 512, 512, bsQ, nullptr, 0, 0,
          Q + (long long)BL * 512, 512, bsQ, nullptr,
          S, 256, bsS, 256, 256, 512, false, 64);

    // 5. both softmaxes, then one merged attend (batch 128)
    row_softmax_kernel<<<dim3(LL, 64), 256, 0, stream>>>(S, SP, MASK + BL);
    col_softmax_kernel<<<dim3(LL, 64), 256, 0, stream>>>(S, SP + 64 * bsS, MASK);
    bgemm(stream, true, SP, 256, 256, bsS, nullptr, 0, 0,
          VTF, 256, (long long)1024 * 256, nullptr,
          ATT, 1024, bsC, 256, 1024, 256, false, 128);

    // 6. compare MLP, merged (M = 32768, K = 2048 via concat)
    bgemm(stream, true, CAT, 1024, 1024, 0, ATT, 1024, 0,
          WTc1, 2048, 0, bc1, Hb, 512, 0, BL2, 512, 2048, true, 1);
    bgemm(stream, true, Hb, 512, 512, 0, nullptr, 0, 0,
          WTc2, 512, 0, bc2, Q, 512, 0, BL2, 512, 512, true, 1);

    // 7. masked position-sum (both sides) -> R32 [64, 1024]
    masked_reduce_kernel<<<dim3(4, BB), 256, 0, stream>>>(Q, MASK, R32);

    // 8. aggregate MLP (fp32) + output
    mlp_par_kernel<<<dim3(8, BB), 256, 0, stream>>>(R32, Wg1, bg1, H64, 1024);
    mlp_par_kernel<<<dim3(8, BB), 256, 0, stream>>>(H64, Wg2, bg2, G, 512);
    out_kernel<<<48, 256, 0, stream>>>(G, Wo, out);
}

// Round 6
// 705.151 us; speedup vs baseline: 4.9599x; 1.1018x over previous
//
#include <hip/hip_runtime.h>
#include <math.h>

#define BB   64
#define LL   256
#define EE   512
#define DD   512
#define BL   (BB * LL)      // 16384
#define BL2  (2 * BL)       // 32768 (prem rows then hypo rows)
#define MAX_DIST 11

typedef __attribute__((ext_vector_type(8))) short bf16x8;
typedef __attribute__((ext_vector_type(8))) unsigned short u16x8;
typedef __attribute__((ext_vector_type(4))) float f32x4;

__device__ __forceinline__ float bf2f(unsigned short u) {
    union { unsigned int u; float f; } v; v.u = ((unsigned int)u) << 16; return v.f;
}
__device__ __forceinline__ unsigned short f2bf(float f) {
    union { float f; unsigned int u; } v; v.f = f;
    unsigned int r = v.u + 0x7FFF + ((v.u >> 16) & 1);   // RNE
    return (unsigned short)(r >> 16);
}

#define GLOAD16(g, l)                                                          \
    __builtin_amdgcn_global_load_lds(                                          \
        (const __attribute__((address_space(1))) void*)(g),                    \
        (__attribute__((address_space(3))) void*)(l), 16, 0, 0)

// ---------------------------------------------------------------------------
// bf16 MFMA GEMM, BK=64, tile 128 x BN (BN = 128 or 256):
//   C = act( [A0|A1] * B^T + bias )
//   A row-major [M, K0+K1] bf16; B row-major [N, K] bf16; C bf16/fp32.
//   M mult of 128, N mult of BN, K/K0 mult of 64.
//   Grid (M/128, N/BN, batch): blocks sharing an A row-slab have IDs
//   differing by multiples of gridDim.x (=M/128, mult of 8) -> same XCD ->
//   A slab served from that XCD's L2 (FETCH reduction).
//   LDS rows of 64 bf16 = 8 x 16B chunks; chunk g of row r at slot g^(r&7)
//   (staging keeps wave-uniform base + lane*16; fragment reads spread all
//   8 dword-phases, 2 lanes each = free, m136).
//   BN=256: wave tile 64x128, acc 128 VGPR -> launch_bounds(256,2).
// ---------------------------------------------------------------------------
template <bool OBF16, int BN>
__global__ __launch_bounds__(256, 2) void bgemm_kernel(
    const unsigned short* __restrict__ A0, int K0, int lda0, long long bsA0,
    const unsigned short* __restrict__ A1, int lda1, long long bsA1,
    const unsigned short* __restrict__ B, int ldb, long long bsB,
    const float* __restrict__ bias,
    void* __restrict__ Cv, int ldc, long long bsC,
    int K, int relu)
{
    constexpr int NI = BN / 32;          // ni tiles per wave (4 or 8)
    __shared__ unsigned short smem[(128 + BN) * 64];
    unsigned short* As = smem;
    unsigned short* Bs = smem + 128 * 64;

    const int tid  = threadIdx.x;
    const int wave = tid >> 6;
    const int lane = tid & 63;
    const int quad = lane >> 4;
    const int l15  = lane & 15;
    const int wm   = (wave >> 1) * 64;
    const int wn   = (wave & 1) * (BN / 2);
    const int row0 = blockIdx.x * 128;
    const int col0 = blockIdx.y * BN;
    const int b    = blockIdx.z;

    const unsigned short* A0b = A0 + (long long)b * bsA0;
    const unsigned short* A1b = A1 ? (A1 + (long long)b * bsA1) : nullptr;
    const unsigned short* Bb  = B + (long long)b * bsB;

    f32x4 acc[4][NI];
#pragma unroll
    for (int i = 0; i < 4; ++i)
#pragma unroll
        for (int j = 0; j < NI; ++j)
            acc[i][j] = (f32x4){0.f, 0.f, 0.f, 0.f};

    for (int kk = 0; kk < K; kk += 64) {
        const unsigned short* Ap; int lda, kloc;
        if (kk < K0) { Ap = A0b; lda = lda0; kloc = kk; }
        else         { Ap = A1b; lda = lda1; kloc = kk - K0; }
        // stage A: 128 rows x 8 chunks = 1024 chunks, 4/thread
#pragma unroll
        for (int it = 0; it < 4; ++it) {
            const int c   = it * 256 + tid;
            const int row = c >> 3;
            const int kch = (c & 7) ^ (row & 7);
            GLOAD16(Ap + (long long)(row0 + row) * lda + kloc + kch * 8,
                    (char*)As + c * 16);
        }
        // stage B: BN rows x 8 chunks, BN/32 per thread
#pragma unroll
        for (int it = 0; it < BN / 32; ++it) {
            const int c   = it * 256 + tid;
            const int row = c >> 3;
            const int kch = (c & 7) ^ (row & 7);
            GLOAD16(Bb + (long long)(col0 + row) * ldb + kk + kch * 8,
                    (char*)Bs + c * 16);
        }
        __syncthreads();

#pragma unroll
        for (int s = 0; s < 2; ++s) {
            bf16x8 fa[4], fb[NI];
#pragma unroll
            for (int mi = 0; mi < 4; ++mi) {
                const int r = wm + mi * 16 + l15;
                const int slot = (s * 4 + quad) ^ (r & 7);
                fa[mi] = *(const bf16x8*)&As[(r * 8 + slot) * 8];
            }
#pragma unroll
            for (int ni = 0; ni < NI; ++ni) {
                const int r = wn + ni * 16 + l15;
                const int slot = (s * 4 + quad) ^ (r & 7);
                fb[ni] = *(const bf16x8*)&Bs[(r * 8 + slot) * 8];
            }
#pragma unroll
            for (int mi = 0; mi < 4; ++mi)
#pragma unroll
                for (int ni = 0; ni < NI; ++ni)
                    acc[mi][ni] = __builtin_amdgcn_mfma_f32_16x16x32_bf16(
                        fa[mi], fb[ni], acc[mi][ni], 0, 0, 0);
        }
        __syncthreads();
    }

    float bv[NI];
#pragma unroll
    for (int ni = 0; ni < NI; ++ni)
        bv[ni] = bias ? bias[col0 + wn + ni * 16 + l15] : 0.f;

    if (OBF16) {
        // coalesced epilogue: 32-row slabs through LDS, 16B packed stores
        float* Ls = (float*)smem;                 // [32][BN+1] fp32
        constexpr int LSW = BN + 1;
        constexpr int CPR = BN / 8;               // 16B chunks per row
        unsigned short* Cb = (unsigned short*)Cv + (long long)b * bsC;
#pragma unroll
        for (int h = 0; h < 4; ++h) {
            if ((wave >> 1) == (h >> 1)) {
                const int mi0 = (h & 1) * 2;
#pragma unroll
                for (int mm = 0; mm < 2; ++mm) {
#pragma unroll
                    for (int ni = 0; ni < NI; ++ni) {
#pragma unroll
                        for (int r = 0; r < 4; ++r) {
                            float x = acc[mi0 + mm][ni][r] + bv[ni];
                            if (relu) x = fmaxf(x, 0.f);
                            Ls[(mm * 16 + quad * 4 + r) * LSW +
                               wn + ni * 16 + l15] = x;
                        }
                    }
                }
            }
            __syncthreads();
#pragma unroll
            for (int it = 0; it < BN / 64; ++it) {
                const int c  = it * 256 + tid;
                const int lr = c / CPR;
                const int cc = (c % CPR) * 8;
                const float* src = &Ls[lr * LSW + cc];
                u16x8 u;
#pragma unroll
                for (int j = 0; j < 8; ++j) u[j] = f2bf(src[j]);
                *(u16x8*)(Cb + (long long)(row0 + h * 32 + lr) * ldc +
                          col0 + cc) = u;
            }
            __syncthreads();
        }
    } else {
        float* Cb = (float*)Cv + (long long)b * bsC;
#pragma unroll
        for (int mi = 0; mi < 4; ++mi)
#pragma unroll
            for (int ni = 0; ni < NI; ++ni) {
                const int colb = col0 + wn + ni * 16 + l15;
#pragma unroll
                for (int r = 0; r < 4; ++r) {
                    const int row = row0 + wm + mi * 16 + quad * 4 + r;
                    float x = acc[mi][ni][r] + bv[ni];
                    if (relu) x = fmaxf(x, 0.f);
                    Cb[(long long)row * ldc + colb] = x;
                }
            }
    }
}

// ---------------------------------------------------------------------------
// All-6 weight convert+transpose: W fp32 [K,512] -> WT bf16 [512,K]
// ---------------------------------------------------------------------------
struct WC6 {
    const float* s[6];
    unsigned short* d[6];
    int K[6];
};
__global__ void wconv6_kernel(WC6 wc)
{
    const int z = blockIdx.z;
    const int K = wc.K[z];
    const int k0 = blockIdx.y * 32;
    if (k0 >= K) return;
    const float* src = wc.s[z];
    unsigned short* dst = wc.d[z];
    __shared__ float tile[32][33];
    const int n0 = blockIdx.x * 32;
#pragma unroll
    for (int i = 0; i < 4; ++i)
        tile[threadIdx.y + i * 8][threadIdx.x] =
            src[(long long)(k0 + threadIdx.y + i * 8) * 512 + n0 + threadIdx.x];
    __syncthreads();
#pragma unroll
    for (int i = 0; i < 4; ++i)
        dst[(long long)(n0 + threadIdx.y + i * 8) * K + k0 + threadIdx.x] =
            f2bf(tile[threadIdx.x][threadIdx.y + i * 8]);
}

// Per-batch bf16 transpose: src batch (bz^bxor) rows [256][lds_] cols c0..C
__global__ void btrans_kernel(const unsigned short* __restrict__ src, int lds_,
                              unsigned short* __restrict__ dst, int C, int bxor)
{
    __shared__ unsigned short tile[32][33];
    const int bz = blockIdx.z;
    const int bs = bz ^ bxor;
    const int c0 = blockIdx.x * 32, l0 = blockIdx.y * 32;
    const unsigned short* s = src + (long long)bs * 256 * lds_;
    unsigned short* d = dst + (long long)bz * C * 256;
#pragma unroll
    for (int i = 0; i < 4; ++i)
        tile[threadIdx.y + i * 8][threadIdx.x] =
            s[(long long)(l0 + threadIdx.y + i * 8) * lds_ + c0 + threadIdx.x];
    __syncthreads();
#pragma unroll
    for (int i = 0; i < 4; ++i)
        d[(long long)(c0 + threadIdx.y + i * 8) * 256 + l0 + threadIdx.x] =
            tile[threadIdx.x][threadIdx.y + i * 8];
}

// Embedding gather (both sentences) + mask
__global__ void embed_kernel(const int* __restrict__ prem_tok,
                             const int* __restrict__ hypo_tok,
                             const float* __restrict__ W,
                             unsigned short* __restrict__ cat,
                             float* __restrict__ mask)
{
    const int row = blockIdx.x;
    const int t   = threadIdx.x;
    const int tok = row < BL ? prem_tok[row] : hypo_tok[row - BL];
    if (t == 0) mask[row] = (tok != 0) ? 1.0f : 0.0f;
    float4 v = ((const float4*)(W + (long long)tok * EE))[t];
    ushort4 o;
    o.x = f2bf(v.x); o.y = f2bf(v.y); o.z = f2bf(v.z); o.w = f2bf(v.w);
    ((ushort4*)(cat + (long long)row * 1024))[t] = o;
}

// ---------------------------------------------------------------------------
// Softmax kernels (fp32 scores in, bf16 probs out), block 256
// ---------------------------------------------------------------------------
__device__ __forceinline__ float block_max(float v, float* red, int tid)
{
    red[tid] = v; __syncthreads();
    for (int st = 128; st > 0; st >>= 1) {
        if (tid < st) red[tid] = fmaxf(red[tid], red[tid + st]);
        __syncthreads();
    }
    float r = red[0]; __syncthreads();
    return r;
}
__device__ __forceinline__ float block_sum(float v, float* red, int tid)
{
    red[tid] = v; __syncthreads();
    for (int st = 128; st > 0; st >>= 1) {
        if (tid < st) red[tid] += red[tid + st];
        __syncthreads();
    }
    float r = red[0]; __syncthreads();
    return r;
}

__global__ void self_softmax_kernel(const float* __restrict__ S,
                                    unsigned short* __restrict__ SP,
                                    const float* __restrict__ mask,
                                    const float* __restrict__ distW)
{
    __shared__ float red[256];
    const int q = blockIdx.x, b = blockIdx.y, j = threadIdx.x;
    float s = S[((long long)b * LL + q) * LL + j];
    int d = j - q;
    d = d > MAX_DIST ? MAX_DIST : (d < -MAX_DIST ? -MAX_DIST : d);
    s += distW[d + MAX_DIST];
    if (j == q) s = -INFINITY;
    if (mask[b * LL + j] == 0.0f) s = -1e9f;
    float mx = block_max(s, red, j);
    float e  = expf(s - mx);
    float sm = block_sum(e, red, j);
    SP[((long long)b * LL + q) * LL + j] = f2bf(e / sm);
}

__global__ void row_softmax_kernel(const float* __restrict__ Z,
                                   unsigned short* __restrict__ SP,
                                   const float* __restrict__ maskK)
{
    __shared__ float red[256];
    const int p = blockIdx.x, b = blockIdx.y, j = threadIdx.x;
    float s = Z[((long long)b * LL + p) * LL + j];
    if (maskK[b * LL + j] == 0.0f) s = -1e9f;
    float mx = block_max(s, red, j);
    float e  = expf(s - mx);
    float sm = block_sum(e, red, j);
    SP[((long long)b * LL + p) * LL + j] = f2bf(e / sm);
}

// col softmax over p, output transposed: SP[b][h][p]
__global__ void col_softmax_kernel(const float* __restrict__ Z,
                                   unsigned short* __restrict__ SP,
                                   const float* __restrict__ maskQ)
{
    __shared__ float red[256];
    const int h = blockIdx.x, b = blockIdx.y, p = threadIdx.x;
    float s = Z[((long long)b * LL + p) * LL + h];
    if (maskQ[b * LL + p] == 0.0f) s = -1e9f;
    float mx = block_max(s, red, p);
    float e  = expf(s - mx);
    float sm = block_sum(e, red, p);
    SP[((long long)b * LL + h) * LL + p] = f2bf(e / sm);
}

// Masked position-sum, both sides: grid (4, 64), block 256.
__global__ void masked_reduce_kernel(const unsigned short* __restrict__ Q,
                                     const float* __restrict__ MASK,
                                     float* __restrict__ R32)
{
    const int side = blockIdx.x >> 1;
    const int c    = (blockIdx.x & 1) * 256 + threadIdx.x;
    const int b    = blockIdx.y;
    const unsigned short* xb = Q + ((long long)(side * BL + b * LL)) * DD + c;
    const float* mb = MASK + side * BL + b * LL;
    float a0 = 0.f, a1 = 0.f, a2 = 0.f, a3 = 0.f;
#pragma unroll 4
    for (int r = 0; r < 64; ++r) {
        a0 = fmaf(bf2f(xb[(r       ) * DD]), mb[r      ], a0);
        a1 = fmaf(bf2f(xb[(r +  64) * DD]), mb[r +  64], a1);
        a2 = fmaf(bf2f(xb[(r + 128) * DD]), mb[r + 128], a2);
        a3 = fmaf(bf2f(xb[(r + 192) * DD]), mb[r + 192], a3);
    }
    R32[b * 1024 + side * 512 + c] = (a0 + a1) + (a2 + a3);
}

// Parallel small fp32 MLP layer: grid (8, BB), block 256
__global__ __launch_bounds__(256) void mlp_par_kernel(
    const float* __restrict__ X, const float* __restrict__ W,
    const float* __restrict__ bias, float* __restrict__ Y, int Kin)
{
    __shared__ float red[4][64];
    const int b  = blockIdx.y;
    const int n  = blockIdx.x * 64 + (threadIdx.x & 63);
    const int ts = threadIdx.x >> 6;
    const int kc = Kin >> 2;
    const float* x = X + (long long)b * Kin + ts * kc;
    const float* w = W + (long long)(ts * kc) * 512 + n;
    float a0 = 0.f, a1 = 0.f;
#pragma unroll 8
    for (int k = 0; k < kc; k += 2) {
        a0 = fmaf(x[k],     w[(long long)k * 512],       a0);
        a1 = fmaf(x[k + 1], w[(long long)(k + 1) * 512], a1);
    }
    red[ts][threadIdx.x & 63] = a0 + a1;
    __syncthreads();
    if (ts == 0) {
        float v = red[0][threadIdx.x] + red[1][threadIdx.x] +
                  red[2][threadIdx.x] + red[3][threadIdx.x] + bias[n];
        Y[b * 512 + n] = fmaxf(v, 0.f);
    }
}

// Final output: one wave per (b,o).  grid 48 x 256 thr = 192 waves.
__global__ void out_kernel(const float* __restrict__ G,
                           const float* __restrict__ Wo,
                           float* __restrict__ out)
{
    const int wid  = blockIdx.x * 4 + (threadIdx.x >> 6);
    const int lane = threadIdx.x & 63;
    const int b = wid / 3, o = wid % 3;
    float acc = 0.f;
#pragma unroll
    for (int j = 0; j < 8; ++j) {
        int d = lane + j * 64;
        acc = fmaf(G[b * DD + d], Wo[d * 3 + o], acc);
    }
#pragma unroll
    for (int st = 32; st > 0; st >>= 1)
        acc += __shfl_down(acc, st, 64);
    if (lane == 0) out[wid] = acc;
}

// ---------------------------------------------------------------------------
// Host-side launcher
// ---------------------------------------------------------------------------
static inline void bgemm(hipStream_t stream, bool obf16, int bn,
                         const unsigned short* A0, int K0, int lda0, long long bsA0,
                         const unsigned short* A1, int lda1, long long bsA1,
                         const unsigned short* B, int ldb, long long bsB,
                         const float* bias,
                         void* C, int ldc, long long bsC,
                         int M, int N, int K, bool relu, int batch)
{
    dim3 grid(M / 128, N / bn, batch);
    if (bn == 256) {
        if (obf16)
            bgemm_kernel<true, 256><<<grid, 256, 0, stream>>>(A0, K0, lda0, bsA0, A1, lda1, bsA1,
                                                              B, ldb, bsB, bias, C, ldc, bsC, K, relu);
        else
            bgemm_kernel<false, 256><<<grid, 256, 0, stream>>>(A0, K0, lda0, bsA0, A1, lda1, bsA1,
                                                               B, ldb, bsB, bias, C, ldc, bsC, K, relu);
    } else {
        if (obf16)
            bgemm_kernel<true, 128><<<grid, 256, 0, stream>>>(A0, K0, lda0, bsA0, A1, lda1, bsA1,
                                                              B, ldb, bsB, bias, C, ldc, bsC, K, relu);
        else
            bgemm_kernel<false, 128><<<grid, 256, 0, stream>>>(A0, K0, lda0, bsA0, A1, lda1, bsA1,
                                                               B, ldb, bsB, bias, C, ldc, bsC, K, relu);
    }
}

extern "C" void kernel_launch(void* const* d_in, const int* in_sizes, int n_in,
                              void* d_out, int out_size, void* d_ws, size_t ws_size,
                              hipStream_t stream)
{
    (void)in_sizes; (void)n_in; (void)out_size; (void)ws_size;

    const int*   prem_tok = (const int*)d_in[0];
    const int*   hypo_tok = (const int*)d_in[1];
    const float* embW = (const float*)d_in[2];
    const float* dW   = (const float*)d_in[3];
    const float* Ws1  = (const float*)d_in[4];
    const float* bs1  = (const float*)d_in[5];
    const float* Ws2  = (const float*)d_in[6];
    const float* bs2  = (const float*)d_in[7];
    const float* Wa1  = (const float*)d_in[8];
    const float* ba1  = (const float*)d_in[9];
    const float* Wa2  = (const float*)d_in[10];
    const float* ba2  = (const float*)d_in[11];
    const float* Wc1  = (const float*)d_in[12];
    const float* bc1  = (const float*)d_in[13];
    const float* Wc2  = (const float*)d_in[14];
    const float* bc2  = (const float*)d_in[15];
    const float* Wg1  = (const float*)d_in[16];
    const float* bg1  = (const float*)d_in[17];
    const float* Wg2  = (const float*)d_in[18];
    const float* bg2  = (const float*)d_in[19];
    const float* Wo   = (const float*)d_in[20];
    float* out = (float*)d_out;

    // ---- workspace carve-up (bytes), ~324 MB ----
    char* ws = (char*)d_ws;
    size_t off = 0;
    auto alloc = [&](size_t bytes) {
        char* p = ws + off; off += (bytes + 255) & ~(size_t)255; return p;
    };
    unsigned short* CAT  = (unsigned short*)alloc((size_t)BL2 * 1024 * 2);
    unsigned short* VTF  = (unsigned short*)alloc((size_t)128 * 1024 * 256 * 2);
    unsigned short* Hb   = (unsigned short*)alloc((size_t)BL2 * 512 * 2);
    unsigned short* Q    = (unsigned short*)alloc((size_t)BL2 * 512 * 2);
    unsigned short* ATT  = (unsigned short*)alloc((size_t)BL2 * 1024 * 2);
    float*          S    = (float*)alloc((size_t)128 * LL * LL * 4);
    unsigned short* SP   = (unsigned short*)alloc((size_t)128 * LL * LL * 2);
    float*          MASK = (float*)alloc((size_t)BL2 * 4);
    float*          R32  = (float*)alloc((size_t)BB * 1024 * 4);
    float*          H64  = (float*)alloc((size_t)BB * 512 * 4);
    float*          G    = (float*)alloc((size_t)BB * 512 * 4);
    unsigned short* WTs1 = (unsigned short*)alloc((size_t)512 * 512 * 2);
    unsigned short* WTs2 = (unsigned short*)alloc((size_t)512 * 512 * 2);
    unsigned short* WTa1 = (unsigned short*)alloc((size_t)1024 * 512 * 2);
    unsigned short* WTa2 = (unsigned short*)alloc((size_t)512 * 512 * 2);
    unsigned short* WTc1 = (unsigned short*)alloc((size_t)2048 * 512 * 2);
    unsigned short* WTc2 = (unsigned short*)alloc((size_t)512 * 512 * 2);

    const long long bsQ = (long long)LL * DD;       // 131072
    const long long bsS = (long long)LL * LL;       // 65536
    const long long bsC = (long long)LL * 1024;     // 262144

    dim3 tb(32, 8);

    // 0. all weights: convert + transpose to [512, K] bf16, one dispatch
    WC6 wc;
    wc.s[0] = Ws1; wc.d[0] = WTs1; wc.K[0] = 512;
    wc.s[1] = Ws2; wc.d[1] = WTs2; wc.K[1] = 512;
    wc.s[2] = Wa1; wc.d[2] = WTa1; wc.K[2] = 1024;
    wc.s[3] = Wa2; wc.d[3] = WTa2; wc.K[3] = 512;
    wc.s[4] = Wc1; wc.d[4] = WTc1; wc.K[4] = 2048;
    wc.s[5] = Wc2; wc.d[5] = WTc2; wc.K[5] = 512;
    wconv6_kernel<<<dim3(16, 64, 6), tb, 0, stream>>>(wc);

    // 1. embeddings + masks (both sentences)
    embed_kernel<<<BL2, 128, 0, stream>>>(prem_tok, hypo_tok, embW, CAT, MASK);

    // 2. self branch, merged (M = 32768, batch = 128)
    bgemm(stream, true, 256, CAT, 512, 1024, 0, nullptr, 0, 0,
          WTs1, 512, 0, bs1, Hb, 512, 0, BL2, 512, 512, true, 1);
    bgemm(stream, true, 256, Hb, 512, 512, 0, nullptr, 0, 0,
          WTs2, 512, 0, bs2, Q, 512, 0, BL2, 512, 512, true, 1);
    btrans_kernel<<<dim3(16, 8, 128), tb, 0, stream>>>(CAT, 1024, VTF, 512, 0);
    bgemm(stream, false, 128, Q, 512, 512, bsQ, nullptr, 0, 0,
          Q, 512, bsQ, nullptr, S, 256, bsS, 256, 256, 512, false, 128);
    self_softmax_kernel<<<dim3(LL, 128), 256, 0, stream>>>(S, SP, MASK, dW);
    bgemm(stream, true, 256, SP, 256, 256, bsS, nullptr, 0, 0,
          VTF, 256, (long long)512 * 256, nullptr,
          CAT + 512, 1024, bsC, 256, 512, 256, false, 128);

    // 3. full V^T, cross-ordered (batch z holds sentence z^64)
    btrans_kernel<<<dim3(32, 8, 128), tb, 0, stream>>>(CAT, 1024, VTF, 1024, 64);

    // 4. inter-attention projections (merged M = 32768)
    bgemm(stream, true, 256, CAT, 1024, 1024, 0, nullptr, 0, 0,
          WTa1, 1024, 0, ba1, Hb, 512, 0, BL2, 512, 1024, true, 1);
    bgemm(stream, true, 256, Hb, 512, 512, 0, nullptr, 0, 0,
          WTa2, 512, 0, ba2, Q, 512, 0, BL2, 512, 512, true, 1);
    bgemm(stream, false, 128, Q, 512, 512, bsQ, nullptr, 0, 0,
          Q + (long long)BL * 512, 512, bsQ, nullptr,
          S, 256, bsS, 256, 256, 512, false, 64);

    // 5. both softmaxes, then one merged attend (batch 128)
    row_softmax_kernel<<<dim3(LL, 64), 256, 0, stream>>>(S, SP, MASK + BL);
    col_softmax_kernel<<<dim3(LL, 64), 256, 0, stream>>>(S, SP + 64 * bsS, MASK);
    bgemm(stream, true, 256, SP, 256, 256, bsS, nullptr, 0, 0,
          VTF, 256, (long long)1024 * 256, nullptr,
          ATT, 1024, bsC, 256, 1024, 256, false, 128);

    // 6. compare MLP, merged (M = 32768, K = 2048 via concat)
    bgemm(stream, true, 256, CAT, 1024, 1024, 0, ATT, 1024, 0,
          WTc1, 2048, 0, bc1, Hb, 512, 0, BL2, 512, 2048, true, 1);
    bgemm(stream, true, 256, Hb, 512, 512, 0, nullptr, 0, 0,
          WTc2, 512, 0, bc2, Q, 512, 0, BL2, 512, 512, true, 1);

    // 7. masked position-sum (both sides) -> R32 [64, 1024]
    masked_reduce_kernel<<<dim3(4, BB), 256, 0, stream>>>(Q, MASK, R32);

    // 8. aggregate MLP (fp32) + output
    mlp_par_kernel<<<dim3(8, BB), 256, 0, stream>>>(R32, Wg1, bg1, H64, 1024);
    mlp_par_kernel<<<dim3(8, BB), 256, 0, stream>>>(H64, Wg2, bg2, G, 512);
    out_kernel<<<48, 256, 0, stream>>>(G, Wo, out);
}

// Round 7
// 630.172 us; speedup vs baseline: 5.5501x; 1.1190x over previous
//
#include <hip/hip_runtime.h>
#include <math.h>

#define BB   64
#define LL   256
#define EE   512
#define DD   512
#define BL   (BB * LL)      // 16384
#define BL2  (2 * BL)       // 32768 (prem rows then hypo rows)
#define MAX_DIST 11

typedef __attribute__((ext_vector_type(8))) short bf16x8;
typedef __attribute__((ext_vector_type(8))) unsigned short u16x8;
typedef __attribute__((ext_vector_type(4))) float f32x4;

__device__ __forceinline__ float bf2f(unsigned short u) {
    union { unsigned int u; float f; } v; v.u = ((unsigned int)u) << 16; return v.f;
}
__device__ __forceinline__ unsigned short f2bf(float f) {
    union { float f; unsigned int u; } v; v.f = f;
    unsigned int r = v.u + 0x7FFF + ((v.u >> 16) & 1);   // RNE
    return (unsigned short)(r >> 16);
}

#define GLOAD16(g, l)                                                          \
    __builtin_amdgcn_global_load_lds(                                          \
        (const __attribute__((address_space(1))) void*)(g),                    \
        (__attribute__((address_space(3))) void*)(l), 16, 0, 0)

// ---------------------------------------------------------------------------
// bf16 MFMA GEMM, BK=64, tile 128x256, 4 waves (wave tile 64x128).
// MODE 0: C = act([A0|A1]*B^T + bias), bf16 out via coalesced LDS epilogue.
// MODE 1: softmax epilogue (requires N==256, gridDim.y==1): apply optional
//         dist-bias/diag(-inf)/key-mask(-1e9), row softmax across the full
//         256-col row (in-wave shuffle + cross-wave LDS), write bf16 probs.
//         B batch index is (b ^ bxor)  ->  z and z^T in one dispatch.
// MODE 2: masked row-reduction epilogue: x=relu(acc+bias), t += x*mask[row],
//         atomicAdd partial column sums into rout [64,1024]; no C write.
// Grid (M/128, N/256, batch): A-slab sharers land on one XCD (L2 reuse).
// LDS: rows of 64 bf16 = 8 x 16B chunks, chunk g of row r at slot g^(r&7).
// ---------------------------------------------------------------------------
template <int MODE>
__global__ __launch_bounds__(256, 2) void bgemm_kernel(
    const unsigned short* __restrict__ A0, int K0, int lda0, long long bsA0,
    const unsigned short* __restrict__ A1, int lda1, long long bsA1,
    const unsigned short* __restrict__ B, int ldb, long long bsB, int bxor,
    const float* __restrict__ bias,
    void* __restrict__ Cv, int ldc, long long bsC,
    int K, int relu,
    const float* __restrict__ smask, const float* __restrict__ distW,
    int diag, int maskXor,
    float* __restrict__ rout, const float* __restrict__ rmask)
{
    constexpr int BN = 256;
    constexpr int NI = 8;
    __shared__ unsigned short smem[(128 + BN) * 64];
    unsigned short* As = smem;
    unsigned short* Bs = smem + 128 * 64;

    const int tid  = threadIdx.x;
    const int wave = tid >> 6;
    const int lane = tid & 63;
    const int quad = lane >> 4;
    const int l15  = lane & 15;
    const int wm   = (wave >> 1) * 64;
    const int wn   = (wave & 1) * 128;
    const int row0 = blockIdx.x * 128;
    const int col0 = blockIdx.y * BN;
    const int b    = blockIdx.z;

    const unsigned short* A0b = A0 + (long long)b * bsA0;
    const unsigned short* A1b = A1 ? (A1 + (long long)b * bsA1) : nullptr;
    const unsigned short* Bb  = B + (long long)(b ^ bxor) * bsB;

    f32x4 acc[4][NI];
#pragma unroll
    for (int i = 0; i < 4; ++i)
#pragma unroll
        for (int j = 0; j < NI; ++j)
            acc[i][j] = (f32x4){0.f, 0.f, 0.f, 0.f};

    for (int kk = 0; kk < K; kk += 64) {
        const unsigned short* Ap; int lda, kloc;
        if (kk < K0) { Ap = A0b; lda = lda0; kloc = kk; }
        else         { Ap = A1b; lda = lda1; kloc = kk - K0; }
#pragma unroll
        for (int it = 0; it < 4; ++it) {
            const int c   = it * 256 + tid;
            const int row = c >> 3;
            const int kch = (c & 7) ^ (row & 7);
            GLOAD16(Ap + (long long)(row0 + row) * lda + kloc + kch * 8,
                    (char*)As + c * 16);
        }
#pragma unroll
        for (int it = 0; it < 8; ++it) {
            const int c   = it * 256 + tid;
            const int row = c >> 3;
            const int kch = (c & 7) ^ (row & 7);
            GLOAD16(Bb + (long long)(col0 + row) * ldb + kk + kch * 8,
                    (char*)Bs + c * 16);
        }
        __syncthreads();

#pragma unroll
        for (int s = 0; s < 2; ++s) {
            bf16x8 fa[4], fb[NI];
#pragma unroll
            for (int mi = 0; mi < 4; ++mi) {
                const int r = wm + mi * 16 + l15;
                const int slot = (s * 4 + quad) ^ (r & 7);
                fa[mi] = *(const bf16x8*)&As[(r * 8 + slot) * 8];
            }
#pragma unroll
            for (int ni = 0; ni < NI; ++ni) {
                const int r = wn + ni * 16 + l15;
                const int slot = (s * 4 + quad) ^ (r & 7);
                fb[ni] = *(const bf16x8*)&Bs[(r * 8 + slot) * 8];
            }
#pragma unroll
            for (int mi = 0; mi < 4; ++mi)
#pragma unroll
                for (int ni = 0; ni < NI; ++ni)
                    acc[mi][ni] = __builtin_amdgcn_mfma_f32_16x16x32_bf16(
                        fa[mi], fb[ni], acc[mi][ni], 0, 0, 0);
        }
        __syncthreads();
    }

    if constexpr (MODE == 2) {
        // masked row-reduce: no C write
        float bv[NI];
#pragma unroll
        for (int ni = 0; ni < NI; ++ni)
            bv[ni] = bias[col0 + wn + ni * 16 + l15];
        float mrow[4][4];
#pragma unroll
        for (int mi = 0; mi < 4; ++mi)
#pragma unroll
            for (int r = 0; r < 4; ++r)
                mrow[mi][r] = rmask[row0 + wm + mi * 16 + quad * 4 + r];
        float t[NI];
#pragma unroll
        for (int ni = 0; ni < NI; ++ni) t[ni] = 0.f;
#pragma unroll
        for (int mi = 0; mi < 4; ++mi)
#pragma unroll
            for (int ni = 0; ni < NI; ++ni)
#pragma unroll
                for (int r = 0; r < 4; ++r) {
                    float x = fmaxf(acc[mi][ni][r] + bv[ni], 0.f);
                    t[ni] = fmaf(x, mrow[mi][r], t[ni]);
                }
#pragma unroll
        for (int ni = 0; ni < NI; ++ni) {
            t[ni] += __shfl_xor(t[ni], 16, 64);
            t[ni] += __shfl_xor(t[ni], 32, 64);
        }
        if (quad == 0) {
            const int sb = row0 >> 8;                       // sentence-batch
            const int base = (sb & 63) * 1024 + (sb >> 6) * 512;
#pragma unroll
            for (int ni = 0; ni < NI; ++ni)
                atomicAdd(rout + base + col0 + wn + ni * 16 + l15, t[ni]);
        }
        return;
    }

    float bv[NI];
    if constexpr (MODE == 0) {
#pragma unroll
        for (int ni = 0; ni < NI; ++ni)
            bv[ni] = bias ? bias[col0 + wn + ni * 16 + l15] : 0.f;
    } else {
#pragma unroll
        for (int ni = 0; ni < NI; ++ni) bv[ni] = 0.f;
    }

    if constexpr (MODE == 1) {
        // fused row softmax over the full 256-col row
        __shared__ float red[4][64];
        const int kb = b ^ maskXor;
        float mk[NI];
#pragma unroll
        for (int ni = 0; ni < NI; ++ni)
            mk[ni] = smask[kb * 256 + wn + ni * 16 + l15];
        float rm[4][4];
#pragma unroll
        for (int mi = 0; mi < 4; ++mi)
#pragma unroll
            for (int r = 0; r < 4; ++r) rm[mi][r] = -INFINITY;
#pragma unroll
        for (int mi = 0; mi < 4; ++mi)
#pragma unroll
            for (int r = 0; r < 4; ++r) {
                const int q = row0 + wm + mi * 16 + quad * 4 + r;
#pragma unroll
                for (int ni = 0; ni < NI; ++ni) {
                    const int j = wn + ni * 16 + l15;
                    float s = acc[mi][ni][r];
                    if (distW) {
                        int d = j - q;
                        d = d > MAX_DIST ? MAX_DIST : (d < -MAX_DIST ? -MAX_DIST : d);
                        s += distW[d + MAX_DIST];
                    }
                    if (diag && j == q) s = -INFINITY;
                    if (mk[ni] == 0.f) s = -1e9f;
                    acc[mi][ni][r] = s;
                    rm[mi][r] = fmaxf(rm[mi][r], s);
                }
            }
#pragma unroll
        for (int mi = 0; mi < 4; ++mi)
#pragma unroll
            for (int r = 0; r < 4; ++r) {
                float v = rm[mi][r];
                v = fmaxf(v, __shfl_xor(v, 1, 64));
                v = fmaxf(v, __shfl_xor(v, 2, 64));
                v = fmaxf(v, __shfl_xor(v, 4, 64));
                v = fmaxf(v, __shfl_xor(v, 8, 64));
                rm[mi][r] = v;
            }
        if (l15 == 0) {
#pragma unroll
            for (int mi = 0; mi < 4; ++mi)
#pragma unroll
                for (int r = 0; r < 4; ++r)
                    red[wave][mi * 16 + quad * 4 + r] = rm[mi][r];
        }
        __syncthreads();
#pragma unroll
        for (int mi = 0; mi < 4; ++mi)
#pragma unroll
            for (int r = 0; r < 4; ++r)
                rm[mi][r] = fmaxf(rm[mi][r],
                                  red[wave ^ 1][mi * 16 + quad * 4 + r]);
        float rs[4][4];
#pragma unroll
        for (int mi = 0; mi < 4; ++mi)
#pragma unroll
            for (int r = 0; r < 4; ++r) rs[mi][r] = 0.f;
#pragma unroll
        for (int mi = 0; mi < 4; ++mi)
#pragma unroll
            for (int ni = 0; ni < NI; ++ni)
#pragma unroll
                for (int r = 0; r < 4; ++r) {
                    float e = __expf(acc[mi][ni][r] - rm[mi][r]);
                    acc[mi][ni][r] = e;
                    rs[mi][r] += e;
                }
#pragma unroll
        for (int mi = 0; mi < 4; ++mi)
#pragma unroll
            for (int r = 0; r < 4; ++r) {
                float v = rs[mi][r];
                v += __shfl_xor(v, 1, 64);
                v += __shfl_xor(v, 2, 64);
                v += __shfl_xor(v, 4, 64);
                v += __shfl_xor(v, 8, 64);
                rs[mi][r] = v;
            }
        __syncthreads();
        if (l15 == 0) {
#pragma unroll
            for (int mi = 0; mi < 4; ++mi)
#pragma unroll
                for (int r = 0; r < 4; ++r)
                    red[wave][mi * 16 + quad * 4 + r] = rs[mi][r];
        }
        __syncthreads();
#pragma unroll
        for (int mi = 0; mi < 4; ++mi)
#pragma unroll
            for (int r = 0; r < 4; ++r) {
                float inv = 1.f / (rs[mi][r] +
                                   red[wave ^ 1][mi * 16 + quad * 4 + r] -
                                   rs[mi][r] * 0.f);
                // note: rs currently holds own-wave partial; combined below
                float tot = rs[mi][r] + red[wave ^ 1][mi * 16 + quad * 4 + r];
                inv = 1.f / tot;
#pragma unroll
                for (int ni = 0; ni < NI; ++ni)
                    acc[mi][ni][r] *= inv;
            }
        __syncthreads();
    }

    // coalesced bf16 epilogue: 32-row slabs through LDS, 16B packed stores
    {
        float* Ls = (float*)smem;                 // [32][257] fp32
        constexpr int LSW = 257;
        unsigned short* Cb = (unsigned short*)Cv + (long long)b * bsC;
#pragma unroll
        for (int h = 0; h < 4; ++h) {
            if ((wave >> 1) == (h >> 1)) {
                const int mi0 = (h & 1) * 2;
#pragma unroll
                for (int mm = 0; mm < 2; ++mm) {
#pragma unroll
                    for (int ni = 0; ni < NI; ++ni) {
#pragma unroll
                        for (int r = 0; r < 4; ++r) {
                            float x = acc[mi0 + mm][ni][r] + bv[ni];
                            if (MODE == 0 && relu) x = fmaxf(x, 0.f);
                            Ls[(mm * 16 + quad * 4 + r) * LSW +
                               wn + ni * 16 + l15] = x;
                        }
                    }
                }
            }
            __syncthreads();
#pragma unroll
            for (int it = 0; it < 4; ++it) {
                const int c  = it * 256 + tid;
                const int lr = c >> 5;           // /32 chunks-per-row
                const int cc = (c & 31) * 8;
                const float* src = &Ls[lr * LSW + cc];
                u16x8 u;
#pragma unroll
                for (int j = 0; j < 8; ++j) u[j] = f2bf(src[j]);
                *(u16x8*)(Cb + (long long)(row0 + h * 32 + lr) * ldc +
                          col0 + cc) = u;
            }
            __syncthreads();
        }
    }
}

// ---------------------------------------------------------------------------
// All-6 weight convert+transpose: W fp32 [K,512] -> WT bf16 [512,K]
// ---------------------------------------------------------------------------
struct WC6 {
    const float* s[6];
    unsigned short* d[6];
    int K[6];
};
__global__ void wconv6_kernel(WC6 wc)
{
    const int z = blockIdx.z;
    const int K = wc.K[z];
    const int k0 = blockIdx.y * 32;
    if (k0 >= K) return;
    const float* src = wc.s[z];
    unsigned short* dst = wc.d[z];
    __shared__ float tile[32][33];
    const int n0 = blockIdx.x * 32;
#pragma unroll
    for (int i = 0; i < 4; ++i)
        tile[threadIdx.y + i * 8][threadIdx.x] =
            src[(long long)(k0 + threadIdx.y + i * 8) * 512 + n0 + threadIdx.x];
    __syncthreads();
#pragma unroll
    for (int i = 0; i < 4; ++i)
        dst[(long long)(n0 + threadIdx.y + i * 8) * K + k0 + threadIdx.x] =
            f2bf(tile[threadIdx.x][threadIdx.y + i * 8]);
}

// Per-batch bf16 transpose: src batch (bz^bxor) rows [256][lds_] cols c0..C
__global__ void btrans_kernel(const unsigned short* __restrict__ src, int lds_,
                              unsigned short* __restrict__ dst, int C, int bxor)
{
    __shared__ unsigned short tile[32][33];
    const int bz = blockIdx.z;
    const int bs = bz ^ bxor;
    const int c0 = blockIdx.x * 32, l0 = blockIdx.y * 32;
    const unsigned short* s = src + (long long)bs * 256 * lds_;
    unsigned short* d = dst + (long long)bz * C * 256;
#pragma unroll
    for (int i = 0; i < 4; ++i)
        tile[threadIdx.y + i * 8][threadIdx.x] =
            s[(long long)(l0 + threadIdx.y + i * 8) * lds_ + c0 + threadIdx.x];
    __syncthreads();
#pragma unroll
    for (int i = 0; i < 4; ++i)
        d[(long long)(c0 + threadIdx.y + i * 8) * 256 + l0 + threadIdx.x] =
            tile[threadIdx.x][threadIdx.y + i * 8];
}

// Embedding gather (both sentences) + mask
__global__ void embed_kernel(const int* __restrict__ prem_tok,
                             const int* __restrict__ hypo_tok,
                             const float* __restrict__ W,
                             unsigned short* __restrict__ cat,
                             float* __restrict__ mask)
{
    const int row = blockIdx.x;
    const int t   = threadIdx.x;
    const int tok = row < BL ? prem_tok[row] : hypo_tok[row - BL];
    if (t == 0) mask[row] = (tok != 0) ? 1.0f : 0.0f;
    float4 v = ((const float4*)(W + (long long)tok * EE))[t];
    ushort4 o;
    o.x = f2bf(v.x); o.y = f2bf(v.y); o.z = f2bf(v.z); o.w = f2bf(v.w);
    ((ushort4*)(cat + (long long)row * 1024))[t] = o;
}

// Parallel small fp32 MLP layer: grid (8, BB), block 256
__global__ __launch_bounds__(256) void mlp_par_kernel(
    const float* __restrict__ X, const float* __restrict__ W,
    const float* __restrict__ bias, float* __restrict__ Y, int Kin)
{
    __shared__ float red[4][64];
    const int b  = blockIdx.y;
    const int n  = blockIdx.x * 64 + (threadIdx.x & 63);
    const int ts = threadIdx.x >> 6;
    const int kc = Kin >> 2;
    const float* x = X + (long long)b * Kin + ts * kc;
    const float* w = W + (long long)(ts * kc) * 512 + n;
    float a0 = 0.f, a1 = 0.f;
#pragma unroll 8
    for (int k = 0; k < kc; k += 2) {
        a0 = fmaf(x[k],     w[(long long)k * 512],       a0);
        a1 = fmaf(x[k + 1], w[(long long)(k + 1) * 512], a1);
    }
    red[ts][threadIdx.x & 63] = a0 + a1;
    __syncthreads();
    if (ts == 0) {
        float v = red[0][threadIdx.x] + red[1][threadIdx.x] +
                  red[2][threadIdx.x] + red[3][threadIdx.x] + bias[n];
        Y[b * 512 + n] = fmaxf(v, 0.f);
    }
}

// Final output: one wave per (b,o).  grid 48 x 256 thr = 192 waves.
__global__ void out_kernel(const float* __restrict__ G,
                           const float* __restrict__ Wo,
                           float* __restrict__ out)
{
    const int wid  = blockIdx.x * 4 + (threadIdx.x >> 6);
    const int lane = threadIdx.x & 63;
    const int b = wid / 3, o = wid % 3;
    float acc = 0.f;
#pragma unroll
    for (int j = 0; j < 8; ++j) {
        int d = lane + j * 64;
        acc = fmaf(G[b * DD + d], Wo[d * 3 + o], acc);
    }
#pragma unroll
    for (int st = 32; st > 0; st >>= 1)
        acc += __shfl_down(acc, st, 64);
    if (lane == 0) out[wid] = acc;
}

// ---------------------------------------------------------------------------
// Host-side launcher
// ---------------------------------------------------------------------------
struct GemmArgs {
    const unsigned short *A0, *A1, *B;
    int K0, lda0, lda1, ldb;
    long long bsA0, bsA1, bsB;
    int bxor;
    const float* bias;
    void* C; int ldc; long long bsC;
    int M, N, K, relu, batch;
    const float* smask; const float* distW; int diag; int maskXor;
    float* rout; const float* rmask;
};

template <int MODE>
static inline void bgemm_launch(hipStream_t stream, const GemmArgs& a)
{
    dim3 grid(a.M / 128, a.N / 256, a.batch);
    bgemm_kernel<MODE><<<grid, 256, 0, stream>>>(
        a.A0, a.K0, a.lda0, a.bsA0, a.A1, a.lda1, a.bsA1,
        a.B, a.ldb, a.bsB, a.bxor, a.bias, a.C, a.ldc, a.bsC,
        a.K, a.relu, a.smask, a.distW, a.diag, a.maskXor, a.rout, a.rmask);
}

extern "C" void kernel_launch(void* const* d_in, const int* in_sizes, int n_in,
                              void* d_out, int out_size, void* d_ws, size_t ws_size,
                              hipStream_t stream)
{
    (void)in_sizes; (void)n_in; (void)out_size; (void)ws_size;

    const int*   prem_tok = (const int*)d_in[0];
    const int*   hypo_tok = (const int*)d_in[1];
    const float* embW = (const float*)d_in[2];
    const float* dW   = (const float*)d_in[3];
    const float* Ws1  = (const float*)d_in[4];
    const float* bs1  = (const float*)d_in[5];
    const float* Ws2  = (const float*)d_in[6];
    const float* bs2  = (const float*)d_in[7];
    const float* Wa1  = (const float*)d_in[8];
    const float* ba1  = (const float*)d_in[9];
    const float* Wa2  = (const float*)d_in[10];
    const float* ba2  = (const float*)d_in[11];
    const float* Wc1  = (const float*)d_in[12];
    const float* bc1  = (const float*)d_in[13];
    const float* Wc2  = (const float*)d_in[14];
    const float* bc2  = (const float*)d_in[15];
    const float* Wg1  = (const float*)d_in[16];
    const float* bg1  = (const float*)d_in[17];
    const float* Wg2  = (const float*)d_in[18];
    const float* bg2  = (const float*)d_in[19];
    const float* Wo   = (const float*)d_in[20];
    float* out = (float*)d_out;

    // ---- workspace carve-up (bytes) ----
    char* ws = (char*)d_ws;
    size_t off = 0;
    auto alloc = [&](size_t bytes) {
        char* p = ws + off; off += (bytes + 255) & ~(size_t)255; return p;
    };
    unsigned short* CAT  = (unsigned short*)alloc((size_t)BL2 * 1024 * 2);
    unsigned short* VTF  = (unsigned short*)alloc((size_t)128 * 1024 * 256 * 2);
    unsigned short* Hb   = (unsigned short*)alloc((size_t)BL2 * 512 * 2);
    unsigned short* Q    = (unsigned short*)alloc((size_t)BL2 * 512 * 2);
    unsigned short* ATT  = (unsigned short*)alloc((size_t)BL2 * 1024 * 2);
    unsigned short* SP   = (unsigned short*)alloc((size_t)128 * LL * LL * 2);
    float*          MASK = (float*)alloc((size_t)BL2 * 4);
    float*          R32  = (float*)alloc((size_t)BB * 1024 * 4);
    float*          H64  = (float*)alloc((size_t)BB * 512 * 4);
    float*          G    = (float*)alloc((size_t)BB * 512 * 4);
    unsigned short* WTs1 = (unsigned short*)alloc((size_t)512 * 512 * 2);
    unsigned short* WTs2 = (unsigned short*)alloc((size_t)512 * 512 * 2);
    unsigned short* WTa1 = (unsigned short*)alloc((size_t)1024 * 512 * 2);
    unsigned short* WTa2 = (unsigned short*)alloc((size_t)512 * 512 * 2);
    unsigned short* WTc1 = (unsigned short*)alloc((size_t)2048 * 512 * 2);
    unsigned short* WTc2 = (unsigned short*)alloc((size_t)512 * 512 * 2);

    const long long bsQ = (long long)LL * DD;       // 131072
    const long long bsS = (long long)LL * LL;       // 65536
    const long long bsC = (long long)LL * 1024;     // 262144

    dim3 tb(32, 8);

    // 0. weights -> [512, K] bf16; zero R32 accumulator
    WC6 wc;
    wc.s[0] = Ws1; wc.d[0] = WTs1; wc.K[0] = 512;
    wc.s[1] = Ws2; wc.d[1] = WTs2; wc.K[1] = 512;
    wc.s[2] = Wa1; wc.d[2] = WTa1; wc.K[2] = 1024;
    wc.s[3] = Wa2; wc.d[3] = WTa2; wc.K[3] = 512;
    wc.s[4] = Wc1; wc.d[4] = WTc1; wc.K[4] = 2048;
    wc.s[5] = Wc2; wc.d[5] = WTc2; wc.K[5] = 512;
    wconv6_kernel<<<dim3(16, 64, 6), tb, 0, stream>>>(wc);
    hipMemsetAsync(R32, 0, (size_t)BB * 1024 * 4, stream);

    // 1. embeddings + masks
    embed_kernel<<<BL2, 128, 0, stream>>>(prem_tok, hypo_tok, embW, CAT, MASK);

    GemmArgs a = {};

    // 2. self MLP (merged M=32768)
    a = {}; a.A0 = CAT; a.K0 = 512; a.lda0 = 1024; a.B = WTs1; a.ldb = 512;
    a.bias = bs1; a.C = Hb; a.ldc = 512; a.M = BL2; a.N = 512; a.K = 512;
    a.relu = 1; a.batch = 1;
    bgemm_launch<0>(stream, a);
    a = {}; a.A0 = Hb; a.K0 = 512; a.lda0 = 512; a.B = WTs2; a.ldb = 512;
    a.bias = bs2; a.C = Q; a.ldc = 512; a.M = BL2; a.N = 512; a.K = 512;
    a.relu = 1; a.batch = 1;
    bgemm_launch<0>(stream, a);

    // x^T per sentence -> VTF area [128][512][256]
    btrans_kernel<<<dim3(16, 8, 128), tb, 0, stream>>>(CAT, 1024, VTF, 512, 0);

    // 3. self scores + fused softmax (dist bias, diag, key mask) -> SP
    a = {}; a.A0 = Q; a.K0 = 512; a.lda0 = 512; a.bsA0 = bsQ;
    a.B = Q; a.ldb = 512; a.bsB = bsQ; a.bxor = 0;
    a.C = SP; a.ldc = 256; a.bsC = bsS; a.M = 256; a.N = 256; a.K = 512;
    a.batch = 128; a.smask = MASK; a.distW = dW; a.diag = 1; a.maskXor = 0;
    bgemm_launch<1>(stream, a);

    // 4. ctx = att @ x -> CAT cols [512,1024)
    a = {}; a.A0 = SP; a.K0 = 256; a.lda0 = 256; a.bsA0 = bsS;
    a.B = VTF; a.ldb = 256; a.bsB = (long long)512 * 256;
    a.C = CAT + 512; a.ldc = 1024; a.bsC = bsC;
    a.M = 256; a.N = 512; a.K = 256; a.batch = 128;
    bgemm_launch<0>(stream, a);

    // 5. full V^T, cross-ordered (batch z holds sentence z^64)
    btrans_kernel<<<dim3(32, 8, 128), tb, 0, stream>>>(CAT, 1024, VTF, 1024, 64);

    // 6. inter projections (merged)
    a = {}; a.A0 = CAT; a.K0 = 1024; a.lda0 = 1024; a.B = WTa1; a.ldb = 1024;
    a.bias = ba1; a.C = Hb; a.ldc = 512; a.M = BL2; a.N = 512; a.K = 1024;
    a.relu = 1; a.batch = 1;
    bgemm_launch<0>(stream, a);
    a = {}; a.A0 = Hb; a.K0 = 512; a.lda0 = 512; a.B = WTa2; a.ldb = 512;
    a.bias = ba2; a.C = Q; a.ldc = 512; a.M = BL2; a.N = 512; a.K = 512;
    a.relu = 1; a.batch = 1;
    bgemm_launch<0>(stream, a);

    // 7. z and z^T + fused row softmax (key = sentence b^64) -> SP
    a = {}; a.A0 = Q; a.K0 = 512; a.lda0 = 512; a.bsA0 = bsQ;
    a.B = Q; a.ldb = 512; a.bsB = bsQ; a.bxor = 64;
    a.C = SP; a.ldc = 256; a.bsC = bsS; a.M = 256; a.N = 256; a.K = 512;
    a.batch = 128; a.smask = MASK; a.distW = nullptr; a.diag = 0; a.maskXor = 64;
    bgemm_launch<1>(stream, a);

    // 8. merged attend: ATT[b] = SP[b] @ V[b^64]
    a = {}; a.A0 = SP; a.K0 = 256; a.lda0 = 256; a.bsA0 = bsS;
    a.B = VTF; a.ldb = 256; a.bsB = (long long)1024 * 256;
    a.C = ATT; a.ldc = 1024; a.bsC = bsC;
    a.M = 256; a.N = 1024; a.K = 256; a.batch = 128;
    bgemm_launch<0>(stream, a);

    // 9. compare MLP layer 1 (K = 2048 via concat)
    a = {}; a.A0 = CAT; a.K0 = 1024; a.lda0 = 1024;
    a.A1 = ATT; a.lda1 = 1024;
    a.B = WTc1; a.ldb = 2048; a.bias = bc1;
    a.C = Hb; a.ldc = 512; a.M = BL2; a.N = 512; a.K = 2048;
    a.relu = 1; a.batch = 1;
    bgemm_launch<0>(stream, a);

    // 10. compare MLP layer 2 + fused masked position-sum -> R32
    a = {}; a.A0 = Hb; a.K0 = 512; a.lda0 = 512; a.B = WTc2; a.ldb = 512;
    a.bias = bc2; a.M = BL2; a.N = 512; a.K = 512; a.relu = 1; a.batch = 1;
    a.rout = R32; a.rmask = MASK; a.C = Hb; // C unused in MODE 2
    bgemm_launch<2>(stream, a);

    // 11. aggregate MLP (fp32) + output
    mlp_par_kernel<<<dim3(8, BB), 256, 0, stream>>>(R32, Wg1, bg1, H64, 1024);
    mlp_par_kernel<<<dim3(8, BB), 256, 0, stream>>>(H64, Wg2, bg2, G, 512);
    out_kernel<<<48, 256, 0, stream>>>(G, Wo, out);
}